// Round 5
// baseline (1076.376 us; speedup 1.0000x reference)
//
#include <hip/hip_runtime.h>
#include <math.h>

#define N_NODES 50000
#define N_EDGES 600000
#define F 128
#define NT 4
#define KTOT (F * (NT + 1))   // 640
#define N_SEG (NT * N_NODES)  // 200000
#define SCAN_BLK 196          // ceil(N_SEG / 1024)
#define NKT 20                // K chunks of 32
#define WELEM (NKT * 8 * 64 * 8)  // 81920 bf16 ELEMENTS per layer (10240 frags x 8)
#define SEG_PER_BLK 64

typedef __attribute__((ext_vector_type(8))) short bf16x8;
typedef __attribute__((ext_vector_type(4))) float f32x4;

__device__ __forceinline__ unsigned short f2b(float f) {
    unsigned u = __float_as_uint(f);
    return (unsigned short)((u + 0x7FFFu + ((u >> 16) & 1u)) >> 16);
}
__device__ __forceinline__ float b2f(unsigned short h) {
    return __uint_as_float(((unsigned)h) << 16);
}

// ---- build pre-swizzled, hi/lo-split combined weights + averaged bias ----
// Whsw/Wlsw layout (per layer): frag index fi = (kt*8 + ct)*64 + lane, 8 bf16 each:
//   element j: Wcat[kt*32 + (lane>>4)*8 + j][ct*16 + (lane&15)]
__global__ __launch_bounds__(256) void build_w_mfma(
    const float* __restrict__ Ws1, const float* __restrict__ Wn1, const float* __restrict__ b1,
    const float* __restrict__ Ws2, const float* __restrict__ Wn2, const float* __restrict__ b2,
    unsigned short* __restrict__ Whsw, unsigned short* __restrict__ Wlsw,
    float* __restrict__ bavg)
{
    int idx = blockIdx.x * 256 + threadIdx.x;
    const int perLayer = NKT * 8 * 64;   // 10240 fragments
    if (idx < 2 * perLayer) {
        int l = idx >= perLayer;
        int rem = idx - l * perLayer;
        int lane = rem & 63;
        int ct = (rem >> 6) & 7;
        int kt = rem >> 9;
        const float* Wsl = l ? Ws2 : Ws1;
        const float* Wnl = l ? Wn2 : Wn1;
        unsigned short* oh = Whsw + (size_t)l * WELEM + (size_t)rem * 8;
        unsigned short* ol = Wlsw + (size_t)l * WELEM + (size_t)rem * 8;
        int c = ct * 16 + (lane & 15);
        int kbase = kt * 32 + (lane >> 4) * 8;
#pragma unroll
        for (int j = 0; j < 8; ++j) {
            int r = kbase + j;
            int p = r >> 7;
            int kk = r & (F - 1);
            float v;
            if (p == 0) {
                v = 0.25f * (Wsl[(0 * F + kk) * F + c] + Wsl[(1 * F + kk) * F + c] +
                             Wsl[(2 * F + kk) * F + c] + Wsl[(3 * F + kk) * F + c]);
            } else {
                v = 0.25f * Wnl[((p - 1) * F + kk) * F + c];
            }
            unsigned short h = f2b(v);
            oh[j] = h;
            ol[j] = f2b(v - b2f(h));
        }
    } else {
        int k = idx - 2 * perLayer;
        if (k < 2 * F) {
            int l = k >> 7;
            int j = k & (F - 1);
            const float* bl = l ? b2 : b1;
            bavg[k] = 0.25f * (bl[j] + bl[F + j] + bl[2 * F + j] + bl[3 * F + j]);
        }
    }
}

// ---------------- CSR build: histogram over (type,dst) buckets ----------------
__global__ __launch_bounds__(256) void hist_kernel(
    const int* __restrict__ dstA, const int* __restrict__ typA, int* __restrict__ counts)
{
    int e = blockIdx.x * 256 + threadIdx.x;
    if (e < N_EDGES) atomicAdd(&counts[typA[e] * N_NODES + dstA[e]], 1);
}

__global__ __launch_bounds__(256) void scan1(int* __restrict__ counts, int* __restrict__ bsum)
{
    __shared__ int sh[256];
    int t = threadIdx.x;
    int base = blockIdx.x * 1024 + t * 4;
    int v[4];
    int tot = 0;
#pragma unroll
    for (int j = 0; j < 4; ++j) {
        int i = base + j;
        v[j] = (i < N_SEG) ? counts[i] : 0;
        tot += v[j];
    }
    sh[t] = tot;
    __syncthreads();
    for (int ofs = 1; ofs < 256; ofs <<= 1) {
        int add = (t >= ofs) ? sh[t - ofs] : 0;
        __syncthreads();
        sh[t] += add;
        __syncthreads();
    }
    int excl = (t > 0) ? sh[t - 1] : 0;
    if (t == 255) bsum[blockIdx.x] = sh[255];
#pragma unroll
    for (int j = 0; j < 4; ++j) {
        int i = base + j;
        if (i < N_SEG) counts[i] = excl;
        excl += v[j];
    }
}

__global__ __launch_bounds__(256) void scan2(int* __restrict__ bsum)
{
    __shared__ int sh[256];
    int t = threadIdx.x;
    sh[t] = (t < SCAN_BLK) ? bsum[t] : 0;
    __syncthreads();
    for (int ofs = 1; ofs < 256; ofs <<= 1) {
        int add = (t >= ofs) ? sh[t - ofs] : 0;
        __syncthreads();
        sh[t] += add;
        __syncthreads();
    }
    int excl = (t > 0) ? sh[t - 1] : 0;
    if (t < SCAN_BLK) bsum[t] = excl;
}

// scan3: finalize global offsets IN PLACE (counts -> off) and copy to cursor
__global__ __launch_bounds__(256) void scan3(
    int* __restrict__ counts, const int* __restrict__ bsum, int* __restrict__ cursor)
{
    int i = blockIdx.x * 256 + threadIdx.x;
    if (i < N_SEG) {
        int v = counts[i] + bsum[i >> 10];
        counts[i] = v;
        cursor[i] = v;
    }
}

// permute: place each edge's packed (seg<<32)|src into its bucket slot
// (after this kernel, cursor[seg] == segment end)
__global__ __launch_bounds__(256) void permute_kernel(
    const int* __restrict__ srcA, const int* __restrict__ dstA, const int* __restrict__ typA,
    int* __restrict__ cursor, unsigned long long* __restrict__ perm64)
{
    int e = blockIdx.x * 256 + threadIdx.x;
    if (e < N_EDGES) {
        int seg = typA[e] * N_NODES + dstA[e];
        int pos = atomicAdd(&cursor[seg], 1);
        perm64[pos] = ((unsigned long long)(unsigned)seg << 32) | (unsigned)srcA[e];
    }
}

// ---------------- edge-parallel gather: 64 segments per block, LDS accumulate ----
__global__ __launch_bounds__(256) void gather_agg2(
    const float* __restrict__ H,
    const unsigned long long* __restrict__ perm64,
    const int* __restrict__ off, const int* __restrict__ segend,
    float* __restrict__ agg)
{
    __shared__ float acc[SEG_PER_BLK][F];   // 32 KB
    const int tid = threadIdx.x;
    const int s0 = blockIdx.x * SEG_PER_BLK;

    // zero LDS tile
    float4 z = make_float4(0.f, 0.f, 0.f, 0.f);
#pragma unroll
    for (int i = 0; i < 8; ++i)
        *(float4*)&((float*)acc)[(i * 256 + tid) * 4] = z;
    __syncthreads();

    const int w = tid >> 6;
    const int lane = tid & 63;
    const int eStart = off[s0];
    const int eEnd = (s0 + SEG_PER_BLK < N_SEG) ? off[s0 + SEG_PER_BLK] : N_EDGES;

    // one wave per edge, block-strided; iterations independent -> loads pipeline
    for (int e = eStart + w; e < eEnd; e += 4) {
        unsigned long long pk = perm64[e];
        int src = (int)(unsigned)(pk & 0xffffffffULL);
        int segl = (int)(unsigned)(pk >> 32) - s0;
        float v0 = H[(size_t)src * F + lane];
        float v1 = H[(size_t)src * F + 64 + lane];
        atomicAdd(&acc[segl][lane], v0);
        atomicAdd(&acc[segl][64 + lane], v1);
    }
    __syncthreads();

    // write out scaled means (zeros for empty segments)
#pragma unroll
    for (int i = 0; i < 8; ++i) {
        int idx = i * 256 + tid;       // 0..2047
        int r = idx >> 5;              // local row 0..63
        int cq = idx & 31;             // float4 index 0..31
        int seg = s0 + r;
        float cntf = (float)(segend[seg] - off[seg]);
        float sc = 1.0f / fmaxf(cntf, 1.0f);
        float4 v = *(float4*)&acc[r][cq * 4];
        v.x *= sc; v.y *= sc; v.z *= sc; v.w *= sc;
        *(float4*)(agg + (size_t)seg * F + cq * 4) = v;
    }
}

// ---------------- MFMA GEMM, bf16x3 split-precision ----------------
// block 256 = 4 waves; tile 64 rows x 128 cols; wave w owns cols [w*32, w*32+32)
__global__ __launch_bounds__(256) void gemm_mfma(
    const float* __restrict__ X,             // [N,F] plane 0
    const float* __restrict__ agg,           // [NT,N,F] pre-scaled means
    const unsigned short* __restrict__ Whsw, // [WELEM] frag-ordered hi (this layer)
    const unsigned short* __restrict__ Wlsw, // [WELEM] frag-ordered lo (this layer)
    const float* __restrict__ bias,          // [F]
    float* __restrict__ out,                 // [N,F]
    int doNormRelu)
{
    __shared__ unsigned short AhS[64][56];   // pitch 56: 16B-aligned frags, ~2-way banks
    __shared__ unsigned short AlS[64][56];
    __shared__ float redb[64][5];
    __shared__ float scl[64];

    const int tid = threadIdx.x;
    const int lane = tid & 63;
    const int w = tid >> 6;
    const int quad = lane >> 4;
    const int l15 = lane & 15;
    const int nodeBase = blockIdx.x * 64;

    f32x4 acc[4][2];
#pragma unroll
    for (int rt = 0; rt < 4; ++rt)
#pragma unroll
        for (int ci = 0; ci < 2; ++ci)
            acc[rt][ci] = (f32x4){0.f, 0.f, 0.f, 0.f};

    const bf16x8* Bh = (const bf16x8*)Whsw;
    const bf16x8* Bl = (const bf16x8*)Wlsw;

    for (int kt = 0; kt < NKT; ++kt) {
        const int p = kt >> 2;               // virtual-A plane
        const int kk0 = (kt & 3) * 32;
        __syncthreads();
#pragma unroll
        for (int i = 0; i < 2; ++i) {
            int idx = i * 256 + tid;
            int r = idx >> 3;
            int cc = (idx & 7) * 4;
            int n = nodeBase + r;
            int nc = n < N_NODES ? n : N_NODES - 1;
            const float* srcp = (p == 0)
                ? (X + (size_t)nc * F + kk0)
                : (agg + ((size_t)(p - 1) * N_NODES + nc) * F + kk0);
            float4 v = *(const float4*)(srcp + cc);
            ushort4 hi, lo;
            hi.x = f2b(v.x); lo.x = f2b(v.x - b2f(hi.x));
            hi.y = f2b(v.y); lo.y = f2b(v.y - b2f(hi.y));
            hi.z = f2b(v.z); lo.z = f2b(v.z - b2f(hi.z));
            hi.w = f2b(v.w); lo.w = f2b(v.w - b2f(hi.w));
            *(ushort4*)&AhS[r][cc] = hi;
            *(ushort4*)&AlS[r][cc] = lo;
        }
        __syncthreads();

        bf16x8 bh[2], bl[2];
#pragma unroll
        for (int ci = 0; ci < 2; ++ci) {
            int fi = (kt * 8 + (w * 2 + ci)) * 64 + lane;
            bh[ci] = Bh[fi];
            bl[ci] = Bl[fi];
        }
        bf16x8 ah[4], al[4];
#pragma unroll
        for (int rt = 0; rt < 4; ++rt) {
            int row = rt * 16 + l15;
            ah[rt] = *(const bf16x8*)&AhS[row][quad * 8];
            al[rt] = *(const bf16x8*)&AlS[row][quad * 8];
        }
#pragma unroll
        for (int rt = 0; rt < 4; ++rt)
#pragma unroll
            for (int ci = 0; ci < 2; ++ci) {
                acc[rt][ci] = __builtin_amdgcn_mfma_f32_16x16x32_bf16(ah[rt], bh[ci], acc[rt][ci], 0, 0, 0);
                acc[rt][ci] = __builtin_amdgcn_mfma_f32_16x16x32_bf16(ah[rt], bl[ci], acc[rt][ci], 0, 0, 0);
                acc[rt][ci] = __builtin_amdgcn_mfma_f32_16x16x32_bf16(al[rt], bh[ci], acc[rt][ci], 0, 0, 0);
            }
    }

    // bias (before normalize, per reference)
    float b0 = bias[w * 32 + l15];
    float b1v = bias[w * 32 + 16 + l15];
#pragma unroll
    for (int rt = 0; rt < 4; ++rt)
#pragma unroll
        for (int r = 0; r < 4; ++r) {
            acc[rt][0][r] += b0;
            acc[rt][1][r] += b1v;
        }

    if (doNormRelu) {
#pragma unroll
        for (int rt = 0; rt < 4; ++rt)
#pragma unroll
            for (int r = 0; r < 4; ++r) {
                float v = acc[rt][0][r] * acc[rt][0][r] + acc[rt][1][r] * acc[rt][1][r];
                v += __shfl_xor(v, 1);
                v += __shfl_xor(v, 2);
                v += __shfl_xor(v, 4);
                v += __shfl_xor(v, 8);
                if (l15 == 0) redb[rt * 16 + quad * 4 + r][w] = v;
            }
        __syncthreads();
        if (tid < 64) {
            float s = redb[tid][0] + redb[tid][1] + redb[tid][2] + redb[tid][3];
            scl[tid] = 1.0f / fmaxf(sqrtf(s), 1e-12f);
        }
        __syncthreads();
#pragma unroll
        for (int rt = 0; rt < 4; ++rt)
#pragma unroll
            for (int r = 0; r < 4; ++r) {
                float sc = scl[rt * 16 + quad * 4 + r];
                acc[rt][0][r] = fmaxf(acc[rt][0][r] * sc, 0.0f);
                acc[rt][1][r] = fmaxf(acc[rt][1][r] * sc, 0.0f);
            }
    }

    // store: C/D layout col=lane&15, row=quad*4+reg
#pragma unroll
    for (int rt = 0; rt < 4; ++rt)
#pragma unroll
        for (int r = 0; r < 4; ++r) {
            int row = rt * 16 + quad * 4 + r;
            int n = nodeBase + row;
            if (n < N_NODES) {
                out[(size_t)n * F + w * 32 + l15] = acc[rt][0][r];
                out[(size_t)n * F + w * 32 + 16 + l15] = acc[rt][1][r];
            }
        }
}

extern "C" void kernel_launch(void* const* d_in, const int* in_sizes, int n_in,
                              void* d_out, int out_size, void* d_ws, size_t ws_size,
                              hipStream_t stream)
{
    const float* x   = (const float*)d_in[0];
    const float* Ws1 = (const float*)d_in[1];
    const float* Wn1 = (const float*)d_in[2];
    const float* b1  = (const float*)d_in[3];
    const float* Ws2 = (const float*)d_in[4];
    const float* Wn2 = (const float*)d_in[5];
    const float* b2  = (const float*)d_in[6];
    const int* edge_index = (const int*)d_in[7];
    const int* edge_type  = (const int*)d_in[8];

    const int* srcA = edge_index;
    const int* dstA = edge_index + N_EDGES;

    // workspace layout
    float* ws   = (float*)d_ws;
    float* agg  = ws;                                        // 25,600,000 f
    float* h1   = agg + (size_t)NT * N_NODES * F;            //  6,400,000 f
    float* bavg = h1 + (size_t)N_NODES * F;                  //        256 f
    unsigned short* Whsw = (unsigned short*)(bavg + 2 * F);  // 2*WELEM u16
    unsigned short* Wlsw = Whsw + (size_t)2 * WELEM;         // 2*WELEM u16
    int* counts = (int*)(Wlsw + (size_t)2 * WELEM);          // N_SEG (becomes off in place)
    int* cursor = counts + N_SEG;                            // N_SEG
    int* bsum   = cursor + N_SEG;                            // 256
    unsigned long long* perm64 = (unsigned long long*)(bsum + 256);  // N_EDGES u64
    int* off = counts;                                       // alias after scan3

    // weights: split + swizzle
    {
        int totalThreads = 2 * NKT * 8 * 64 + 2 * F;         // 20736
        hipLaunchKernelGGL(build_w_mfma, dim3((totalThreads + 255) / 256), dim3(256), 0, stream,
                           Ws1, Wn1, b1, Ws2, Wn2, b2, Whsw, Wlsw, bavg);
    }

    // ---------- CSR build (once; shared by both layers) ----------
    hipMemsetAsync(counts, 0, (size_t)N_SEG * sizeof(int), stream);
    hipLaunchKernelGGL(hist_kernel, dim3((N_EDGES + 255) / 256), dim3(256), 0, stream,
                       dstA, edge_type, counts);
    hipLaunchKernelGGL(scan1, dim3(SCAN_BLK), dim3(256), 0, stream, counts, bsum);
    hipLaunchKernelGGL(scan2, dim3(1), dim3(256), 0, stream, bsum);
    hipLaunchKernelGGL(scan3, dim3((N_SEG + 255) / 256), dim3(256), 0, stream,
                       counts, bsum, cursor);
    hipLaunchKernelGGL(permute_kernel, dim3((N_EDGES + 255) / 256), dim3(256), 0, stream,
                       srcA, dstA, edge_type, cursor, perm64);
    // off[seg] = start, cursor[seg] = end

    // ---------- layer 1 ----------
    hipLaunchKernelGGL(gather_agg2, dim3(N_SEG / SEG_PER_BLK), dim3(256), 0, stream,
                       x, perm64, off, cursor, agg);
    hipLaunchKernelGGL(gemm_mfma, dim3((N_NODES + 63) / 64), dim3(256), 0, stream,
                       x, agg, Whsw, Wlsw, bavg, h1, 1);

    // ---------- layer 2 ----------
    hipLaunchKernelGGL(gather_agg2, dim3(N_SEG / SEG_PER_BLK), dim3(256), 0, stream,
                       h1, perm64, off, cursor, agg);
    hipLaunchKernelGGL(gemm_mfma, dim3((N_NODES + 63) / 64), dim3(256), 0, stream,
                       h1, agg, Whsw + WELEM, Wlsw + WELEM, bavg + F, (float*)d_out, 0);
}

// Round 6
// 385.907 us; speedup vs baseline: 2.7892x; 2.7892x over previous
//
#include <hip/hip_runtime.h>
#include <math.h>

#define N_NODES 50000
#define N_EDGES 600000
#define F 128
#define NT 4
#define KTOT (F * (NT + 1))   // 640
#define N_SEG (NT * N_NODES)  // 200000
#define SCAN_BLK 196          // ceil(N_SEG / 1024)
#define NKT 20                // K chunks of 32
#define WELEM (NKT * 8 * 64 * 8)  // 81920 bf16 ELEMENTS per layer

typedef __attribute__((ext_vector_type(8))) short bf16x8;
typedef __attribute__((ext_vector_type(4))) float f32x4;

__device__ __forceinline__ unsigned short f2b(float f) {
    unsigned u = __float_as_uint(f);
    return (unsigned short)((u + 0x7FFFu + ((u >> 16) & 1u)) >> 16);
}
__device__ __forceinline__ float b2f(unsigned short h) {
    return __uint_as_float(((unsigned)h) << 16);
}

// ---- build pre-swizzled, hi/lo-split combined weights + averaged bias ----
__global__ __launch_bounds__(256) void build_w_mfma(
    const float* __restrict__ Ws1, const float* __restrict__ Wn1, const float* __restrict__ b1,
    const float* __restrict__ Ws2, const float* __restrict__ Wn2, const float* __restrict__ b2,
    unsigned short* __restrict__ Whsw, unsigned short* __restrict__ Wlsw,
    float* __restrict__ bavg)
{
    int idx = blockIdx.x * 256 + threadIdx.x;
    const int perLayer = NKT * 8 * 64;   // 10240 fragments
    if (idx < 2 * perLayer) {
        int l = idx >= perLayer;
        int rem = idx - l * perLayer;
        int lane = rem & 63;
        int ct = (rem >> 6) & 7;
        int kt = rem >> 9;
        const float* Wsl = l ? Ws2 : Ws1;
        const float* Wnl = l ? Wn2 : Wn1;
        unsigned short* oh = Whsw + (size_t)l * WELEM + (size_t)rem * 8;
        unsigned short* ol = Wlsw + (size_t)l * WELEM + (size_t)rem * 8;
        int c = ct * 16 + (lane & 15);
        int kbase = kt * 32 + (lane >> 4) * 8;
#pragma unroll
        for (int j = 0; j < 8; ++j) {
            int r = kbase + j;
            int p = r >> 7;
            int kk = r & (F - 1);
            float v;
            if (p == 0) {
                v = 0.25f * (Wsl[(0 * F + kk) * F + c] + Wsl[(1 * F + kk) * F + c] +
                             Wsl[(2 * F + kk) * F + c] + Wsl[(3 * F + kk) * F + c]);
            } else {
                v = 0.25f * Wnl[((p - 1) * F + kk) * F + c];
            }
            unsigned short h = f2b(v);
            oh[j] = h;
            ol[j] = f2b(v - b2f(h));
        }
    } else {
        int k = idx - 2 * perLayer;
        if (k < 2 * F) {
            int l = k >> 7;
            int j = k & (F - 1);
            const float* bl = l ? b2 : b1;
            bavg[k] = 0.25f * (bl[j] + bl[F + j] + bl[2 * F + j] + bl[3 * F + j]);
        }
    }
}

// ---------------- CSR build: histogram over (type,dst) buckets ----------------
__global__ __launch_bounds__(256) void hist_kernel(
    const int* __restrict__ dstA, const int* __restrict__ typA, int* __restrict__ counts)
{
    int e = blockIdx.x * 256 + threadIdx.x;
    if (e < N_EDGES) atomicAdd(&counts[typA[e] * N_NODES + dstA[e]], 1);
}

__global__ __launch_bounds__(256) void scan1(int* __restrict__ counts, int* __restrict__ bsum)
{
    __shared__ int sh[256];
    int t = threadIdx.x;
    int base = blockIdx.x * 1024 + t * 4;
    int v[4];
    int tot = 0;
#pragma unroll
    for (int j = 0; j < 4; ++j) {
        int i = base + j;
        v[j] = (i < N_SEG) ? counts[i] : 0;
        tot += v[j];
    }
    sh[t] = tot;
    __syncthreads();
    for (int ofs = 1; ofs < 256; ofs <<= 1) {
        int add = (t >= ofs) ? sh[t - ofs] : 0;
        __syncthreads();
        sh[t] += add;
        __syncthreads();
    }
    int excl = (t > 0) ? sh[t - 1] : 0;
    if (t == 255) bsum[blockIdx.x] = sh[255];
#pragma unroll
    for (int j = 0; j < 4; ++j) {
        int i = base + j;
        if (i < N_SEG) counts[i] = excl;
        excl += v[j];
    }
}

__global__ __launch_bounds__(256) void scan2(int* __restrict__ bsum)
{
    __shared__ int sh[256];
    int t = threadIdx.x;
    sh[t] = (t < SCAN_BLK) ? bsum[t] : 0;
    __syncthreads();
    for (int ofs = 1; ofs < 256; ofs <<= 1) {
        int add = (t >= ofs) ? sh[t - ofs] : 0;
        __syncthreads();
        sh[t] += add;
        __syncthreads();
    }
    int excl = (t > 0) ? sh[t - 1] : 0;
    if (t < SCAN_BLK) bsum[t] = excl;
}

// scan3: finalize global offsets IN PLACE (counts -> off) and copy to cursor
__global__ __launch_bounds__(256) void scan3(
    int* __restrict__ counts, const int* __restrict__ bsum, int* __restrict__ cursor)
{
    int i = blockIdx.x * 256 + threadIdx.x;
    if (i < N_SEG) {
        int v = counts[i] + bsum[i >> 10];
        counts[i] = v;
        cursor[i] = v;
    }
}

// permute: place each edge's src id into its bucket slot
// (after this kernel, cursor[seg] == segment end)
__global__ __launch_bounds__(256) void permute_kernel(
    const int* __restrict__ srcA, const int* __restrict__ dstA, const int* __restrict__ typA,
    int* __restrict__ cursor, int* __restrict__ perm)
{
    int e = blockIdx.x * 256 + threadIdx.x;
    if (e < N_EDGES) {
        int pos = atomicAdd(&cursor[typA[e] * N_NODES + dstA[e]], 1);
        perm[pos] = srcA[e];
    }
}

// ---------------- gather-aggregate: one wave per segment, 4-edge batches ----------------
// lanes 0-3 fetch 4 perm entries in one request; 4 independent row-loads in flight
__global__ __launch_bounds__(256) void gather_agg(
    const float* __restrict__ H, const int* __restrict__ perm,
    const int* __restrict__ off, const int* __restrict__ segend,
    float* __restrict__ agg)
{
    int seg = blockIdx.x * 4 + (threadIdx.x >> 6);
    int lane = threadIdx.x & 63;
    if (seg >= N_SEG) return;
    int start = off[seg];
    int end = segend[seg];
    float sx = 0.0f, sy = 0.0f;
    for (int b = start; b < end; b += 4) {
        int pidx = b + (lane & 3);
        int pl = perm[pidx < end ? pidx : (end - 1)];
        int nb = end - b;                 // wave-uniform remaining count
        int s0 = __shfl(pl, 0);
        int s1 = __shfl(pl, 1);
        int s2 = __shfl(pl, 2);
        int s3 = __shfl(pl, 3);
        float2 a0 = ((const float2*)(H + (size_t)s0 * F))[lane];
        sx += a0.x; sy += a0.y;
        if (nb > 1) {
            float2 a1 = ((const float2*)(H + (size_t)s1 * F))[lane];
            sx += a1.x; sy += a1.y;
        }
        if (nb > 2) {
            float2 a2 = ((const float2*)(H + (size_t)s2 * F))[lane];
            sx += a2.x; sy += a2.y;
        }
        if (nb > 3) {
            float2 a3 = ((const float2*)(H + (size_t)s3 * F))[lane];
            sx += a3.x; sy += a3.y;
        }
    }
    float sc = 1.0f / fmaxf((float)(end - start), 1.0f);
    ((float2*)(agg + (size_t)seg * F))[lane] = make_float2(sx * sc, sy * sc);
}

// ---------------- MFMA GEMM, bf16x3 split-precision ----------------
// block 256 = 4 waves; tile 64 rows x 128 cols; wave w owns cols [w*32, w*32+32)
__global__ __launch_bounds__(256) void gemm_mfma(
    const float* __restrict__ X,             // [N,F] plane 0
    const float* __restrict__ agg,           // [NT,N,F] pre-scaled means
    const unsigned short* __restrict__ Whsw, // [WELEM] frag-ordered hi (this layer)
    const unsigned short* __restrict__ Wlsw, // [WELEM] frag-ordered lo (this layer)
    const float* __restrict__ bias,          // [F]
    float* __restrict__ out,                 // [N,F]
    int doNormRelu)
{
    __shared__ unsigned short AhS[64][56];   // pitch 56: 16B-aligned frags, ~2-way banks
    __shared__ unsigned short AlS[64][56];
    __shared__ float redb[64][5];
    __shared__ float scl[64];

    const int tid = threadIdx.x;
    const int lane = tid & 63;
    const int w = tid >> 6;
    const int quad = lane >> 4;
    const int l15 = lane & 15;
    const int nodeBase = blockIdx.x * 64;

    f32x4 acc[4][2];
#pragma unroll
    for (int rt = 0; rt < 4; ++rt)
#pragma unroll
        for (int ci = 0; ci < 2; ++ci)
            acc[rt][ci] = (f32x4){0.f, 0.f, 0.f, 0.f};

    const bf16x8* Bh = (const bf16x8*)Whsw;
    const bf16x8* Bl = (const bf16x8*)Wlsw;

    for (int kt = 0; kt < NKT; ++kt) {
        const int p = kt >> 2;               // virtual-A plane
        const int kk0 = (kt & 3) * 32;
        __syncthreads();
#pragma unroll
        for (int i = 0; i < 2; ++i) {
            int idx = i * 256 + tid;
            int r = idx >> 3;
            int cc = (idx & 7) * 4;
            int n = nodeBase + r;
            int nc = n < N_NODES ? n : N_NODES - 1;
            const float* srcp = (p == 0)
                ? (X + (size_t)nc * F + kk0)
                : (agg + ((size_t)(p - 1) * N_NODES + nc) * F + kk0);
            float4 v = *(const float4*)(srcp + cc);
            ushort4 hi, lo;
            hi.x = f2b(v.x); lo.x = f2b(v.x - b2f(hi.x));
            hi.y = f2b(v.y); lo.y = f2b(v.y - b2f(hi.y));
            hi.z = f2b(v.z); lo.z = f2b(v.z - b2f(hi.z));
            hi.w = f2b(v.w); lo.w = f2b(v.w - b2f(hi.w));
            *(ushort4*)&AhS[r][cc] = hi;
            *(ushort4*)&AlS[r][cc] = lo;
        }
        __syncthreads();

        bf16x8 bh[2], bl[2];
#pragma unroll
        for (int ci = 0; ci < 2; ++ci) {
            int fi = (kt * 8 + (w * 2 + ci)) * 64 + lane;
            bh[ci] = Bh[fi];
            bl[ci] = Bl[fi];
        }
        bf16x8 ah[4], al[4];
#pragma unroll
        for (int rt = 0; rt < 4; ++rt) {
            int row = rt * 16 + l15;
            ah[rt] = *(const bf16x8*)&AhS[row][quad * 8];
            al[rt] = *(const bf16x8*)&AlS[row][quad * 8];
        }
#pragma unroll
        for (int rt = 0; rt < 4; ++rt)
#pragma unroll
            for (int ci = 0; ci < 2; ++ci) {
                acc[rt][ci] = __builtin_amdgcn_mfma_f32_16x16x32_bf16(ah[rt], bh[ci], acc[rt][ci], 0, 0, 0);
                acc[rt][ci] = __builtin_amdgcn_mfma_f32_16x16x32_bf16(ah[rt], bl[ci], acc[rt][ci], 0, 0, 0);
                acc[rt][ci] = __builtin_amdgcn_mfma_f32_16x16x32_bf16(al[rt], bh[ci], acc[rt][ci], 0, 0, 0);
            }
    }

    // bias (before normalize, per reference)
    float b0 = bias[w * 32 + l15];
    float b1v = bias[w * 32 + 16 + l15];
#pragma unroll
    for (int rt = 0; rt < 4; ++rt)
#pragma unroll
        for (int r = 0; r < 4; ++r) {
            acc[rt][0][r] += b0;
            acc[rt][1][r] += b1v;
        }

    if (doNormRelu) {
#pragma unroll
        for (int rt = 0; rt < 4; ++rt)
#pragma unroll
            for (int r = 0; r < 4; ++r) {
                float v = acc[rt][0][r] * acc[rt][0][r] + acc[rt][1][r] * acc[rt][1][r];
                v += __shfl_xor(v, 1);
                v += __shfl_xor(v, 2);
                v += __shfl_xor(v, 4);
                v += __shfl_xor(v, 8);
                if (l15 == 0) redb[rt * 16 + quad * 4 + r][w] = v;
            }
        __syncthreads();
        if (tid < 64) {
            float s = redb[tid][0] + redb[tid][1] + redb[tid][2] + redb[tid][3];
            scl[tid] = 1.0f / fmaxf(sqrtf(s), 1e-12f);
        }
        __syncthreads();
#pragma unroll
        for (int rt = 0; rt < 4; ++rt)
#pragma unroll
            for (int r = 0; r < 4; ++r) {
                float sc = scl[rt * 16 + quad * 4 + r];
                acc[rt][0][r] = fmaxf(acc[rt][0][r] * sc, 0.0f);
                acc[rt][1][r] = fmaxf(acc[rt][1][r] * sc, 0.0f);
            }
    }

    // store: C/D layout col=lane&15, row=quad*4+reg
#pragma unroll
    for (int rt = 0; rt < 4; ++rt)
#pragma unroll
        for (int r = 0; r < 4; ++r) {
            int row = rt * 16 + quad * 4 + r;
            int n = nodeBase + row;
            if (n < N_NODES) {
                out[(size_t)n * F + w * 32 + l15] = acc[rt][0][r];
                out[(size_t)n * F + w * 32 + 16 + l15] = acc[rt][1][r];
            }
        }
}

extern "C" void kernel_launch(void* const* d_in, const int* in_sizes, int n_in,
                              void* d_out, int out_size, void* d_ws, size_t ws_size,
                              hipStream_t stream)
{
    const float* x   = (const float*)d_in[0];
    const float* Ws1 = (const float*)d_in[1];
    const float* Wn1 = (const float*)d_in[2];
    const float* b1  = (const float*)d_in[3];
    const float* Ws2 = (const float*)d_in[4];
    const float* Wn2 = (const float*)d_in[5];
    const float* b2  = (const float*)d_in[6];
    const int* edge_index = (const int*)d_in[7];
    const int* edge_type  = (const int*)d_in[8];

    const int* srcA = edge_index;
    const int* dstA = edge_index + N_EDGES;

    // workspace layout
    float* ws   = (float*)d_ws;
    float* agg  = ws;                                        // 25,600,000 f
    float* h1   = agg + (size_t)NT * N_NODES * F;            //  6,400,000 f
    float* bavg = h1 + (size_t)N_NODES * F;                  //        256 f
    unsigned short* Whsw = (unsigned short*)(bavg + 2 * F);  // 2*WELEM u16
    unsigned short* Wlsw = Whsw + (size_t)2 * WELEM;         // 2*WELEM u16
    int* counts = (int*)(Wlsw + (size_t)2 * WELEM);          // N_SEG (becomes off in place)
    int* cursor = counts + N_SEG;                            // N_SEG
    int* bsum   = cursor + N_SEG;                            // 256
    int* perm   = bsum + 256;                                // N_EDGES
    int* off    = counts;                                    // alias after scan3

    // weights: split + swizzle
    {
        int totalThreads = 2 * NKT * 8 * 64 + 2 * F;         // 20736
        hipLaunchKernelGGL(build_w_mfma, dim3((totalThreads + 255) / 256), dim3(256), 0, stream,
                           Ws1, Wn1, b1, Ws2, Wn2, b2, Whsw, Wlsw, bavg);
    }

    // ---------- CSR build (once; shared by both layers) ----------
    hipMemsetAsync(counts, 0, (size_t)N_SEG * sizeof(int), stream);
    hipLaunchKernelGGL(hist_kernel, dim3((N_EDGES + 255) / 256), dim3(256), 0, stream,
                       dstA, edge_type, counts);
    hipLaunchKernelGGL(scan1, dim3(SCAN_BLK), dim3(256), 0, stream, counts, bsum);
    hipLaunchKernelGGL(scan2, dim3(1), dim3(256), 0, stream, bsum);
    hipLaunchKernelGGL(scan3, dim3((N_SEG + 255) / 256), dim3(256), 0, stream,
                       counts, bsum, cursor);
    hipLaunchKernelGGL(permute_kernel, dim3((N_EDGES + 255) / 256), dim3(256), 0, stream,
                       srcA, dstA, edge_type, cursor, perm);
    // off[seg] = start, cursor[seg] = end

    // ---------- layer 1 ----------
    hipLaunchKernelGGL(gather_agg, dim3(N_SEG / 4), dim3(256), 0, stream,
                       x, perm, off, cursor, agg);
    hipLaunchKernelGGL(gemm_mfma, dim3((N_NODES + 63) / 64), dim3(256), 0, stream,
                       x, agg, Whsw, Wlsw, bavg, h1, 1);

    // ---------- layer 2 ----------
    hipLaunchKernelGGL(gather_agg, dim3(N_SEG / 4), dim3(256), 0, stream,
                       h1, perm, off, cursor, agg);
    hipLaunchKernelGGL(gemm_mfma, dim3((N_NODES + 63) / 64), dim3(256), 0, stream,
                       h1, agg, Whsw + WELEM, Wlsw + WELEM, bavg + F, (float*)d_out, 0);
}

// Round 7
// 379.880 us; speedup vs baseline: 2.8335x; 1.0159x over previous
//
#include <hip/hip_runtime.h>
#include <math.h>

#define N_NODES 50000
#define N_EDGES 600000
#define F 128
#define NT 4
#define KTOT (F * (NT + 1))   // 640
#define N_SEG (NT * N_NODES)  // 200000
#define SCAN_BLK 196          // ceil(N_SEG / 1024)
#define NKT 20                // K chunks of 32
#define WELEM (NKT * 8 * 64 * 8)  // 81920 bf16 ELEMENTS per layer

typedef __attribute__((ext_vector_type(8))) short bf16x8;
typedef __attribute__((ext_vector_type(4))) float f32x4;

__device__ __forceinline__ unsigned short f2b(float f) {
    unsigned u = __float_as_uint(f);
    return (unsigned short)((u + 0x7FFFu + ((u >> 16) & 1u)) >> 16);
}
__device__ __forceinline__ float b2f(unsigned short h) {
    return __uint_as_float(((unsigned)h) << 16);
}

// ---- build pre-swizzled, hi/lo-split combined weights + averaged bias ----
__global__ __launch_bounds__(256) void build_w_mfma(
    const float* __restrict__ Ws1, const float* __restrict__ Wn1, const float* __restrict__ b1,
    const float* __restrict__ Ws2, const float* __restrict__ Wn2, const float* __restrict__ b2,
    unsigned short* __restrict__ Whsw, unsigned short* __restrict__ Wlsw,
    float* __restrict__ bavg)
{
    int idx = blockIdx.x * 256 + threadIdx.x;
    const int perLayer = NKT * 8 * 64;   // 10240 fragments
    if (idx < 2 * perLayer) {
        int l = idx >= perLayer;
        int rem = idx - l * perLayer;
        int lane = rem & 63;
        int ct = (rem >> 6) & 7;
        int kt = rem >> 9;
        const float* Wsl = l ? Ws2 : Ws1;
        const float* Wnl = l ? Wn2 : Wn1;
        unsigned short* oh = Whsw + (size_t)l * WELEM + (size_t)rem * 8;
        unsigned short* ol = Wlsw + (size_t)l * WELEM + (size_t)rem * 8;
        int c = ct * 16 + (lane & 15);
        int kbase = kt * 32 + (lane >> 4) * 8;
#pragma unroll
        for (int j = 0; j < 8; ++j) {
            int r = kbase + j;
            int p = r >> 7;
            int kk = r & (F - 1);
            float v;
            if (p == 0) {
                v = 0.25f * (Wsl[(0 * F + kk) * F + c] + Wsl[(1 * F + kk) * F + c] +
                             Wsl[(2 * F + kk) * F + c] + Wsl[(3 * F + kk) * F + c]);
            } else {
                v = 0.25f * Wnl[((p - 1) * F + kk) * F + c];
            }
            unsigned short h = f2b(v);
            oh[j] = h;
            ol[j] = f2b(v - b2f(h));
        }
    } else {
        int k = idx - 2 * perLayer;
        if (k < 2 * F) {
            int l = k >> 7;
            int j = k & (F - 1);
            const float* bl = l ? b2 : b1;
            bavg[k] = 0.25f * (bl[j] + bl[F + j] + bl[2 * F + j] + bl[3 * F + j]);
        }
    }
}

// ---------------- CSR build: histogram over (dst,type) buckets: seg = dst*4 + t ----
__global__ __launch_bounds__(256) void hist_kernel(
    const int* __restrict__ dstA, const int* __restrict__ typA, int* __restrict__ counts)
{
    int e = blockIdx.x * 256 + threadIdx.x;
    if (e < N_EDGES) atomicAdd(&counts[dstA[e] * NT + typA[e]], 1);
}

__global__ __launch_bounds__(256) void scan1(int* __restrict__ counts, int* __restrict__ bsum)
{
    __shared__ int sh[256];
    int t = threadIdx.x;
    int base = blockIdx.x * 1024 + t * 4;
    int v[4];
    int tot = 0;
#pragma unroll
    for (int j = 0; j < 4; ++j) {
        int i = base + j;
        v[j] = (i < N_SEG) ? counts[i] : 0;
        tot += v[j];
    }
    sh[t] = tot;
    __syncthreads();
    for (int ofs = 1; ofs < 256; ofs <<= 1) {
        int add = (t >= ofs) ? sh[t - ofs] : 0;
        __syncthreads();
        sh[t] += add;
        __syncthreads();
    }
    int excl = (t > 0) ? sh[t - 1] : 0;
    if (t == 255) bsum[blockIdx.x] = sh[255];
#pragma unroll
    for (int j = 0; j < 4; ++j) {
        int i = base + j;
        if (i < N_SEG) counts[i] = excl;
        excl += v[j];
    }
}

__global__ __launch_bounds__(256) void scan2(int* __restrict__ bsum)
{
    __shared__ int sh[256];
    int t = threadIdx.x;
    sh[t] = (t < SCAN_BLK) ? bsum[t] : 0;
    __syncthreads();
    for (int ofs = 1; ofs < 256; ofs <<= 1) {
        int add = (t >= ofs) ? sh[t - ofs] : 0;
        __syncthreads();
        sh[t] += add;
        __syncthreads();
    }
    int excl = (t > 0) ? sh[t - 1] : 0;
    if (t < SCAN_BLK) bsum[t] = excl;
}

// scan3: finalize global offsets IN PLACE (counts -> off) and copy to cursor
__global__ __launch_bounds__(256) void scan3(
    int* __restrict__ counts, const int* __restrict__ bsum, int* __restrict__ cursor)
{
    int i = blockIdx.x * 256 + threadIdx.x;
    if (i < N_SEG) {
        int v = counts[i] + bsum[i >> 10];
        counts[i] = v;
        cursor[i] = v;
    }
}

// permute: place each edge's packed (src | t<<16) into its bucket slot (src < 65536)
// (after this kernel, cursor[seg] == segment end)
__global__ __launch_bounds__(256) void permute_kernel(
    const int* __restrict__ srcA, const int* __restrict__ dstA, const int* __restrict__ typA,
    int* __restrict__ cursor, int* __restrict__ perm)
{
    int e = blockIdx.x * 256 + threadIdx.x;
    if (e < N_EDGES) {
        int t = typA[e];
        int pos = atomicAdd(&cursor[dstA[e] * NT + t], 1);
        perm[pos] = srcA[e] | (t << 16);
    }
}

// ---------------- gather-aggregate: one wave per NODE (all 4 type-segments) ----------
// avg 12 edges/node; 8-deep batches of independent 512B row-loads
__global__ __launch_bounds__(256) void gather_agg(
    const float* __restrict__ H, const int* __restrict__ perm,
    const int* __restrict__ off, const int* __restrict__ segend,
    float* __restrict__ agg)
{
    int node = blockIdx.x * 4 + (threadIdx.x >> 6);
    int lane = threadIdx.x & 63;
    if (node >= N_NODES) return;

    // lanes 0-3 fetch this node's 4 segment bounds
    int st = 0, en = 0;
    if (lane < 4) {
        st = off[node * NT + lane];
        en = segend[node * NT + lane];
    }
    int start = __shfl(st, 0);
    int end   = __shfl(en, 3);
    float c0 = (float)(__shfl(en, 0) - __shfl(st, 0));
    float c1 = (float)(__shfl(en, 1) - __shfl(st, 1));
    float c2 = (float)(__shfl(en, 2) - __shfl(st, 2));
    float c3 = (float)(__shfl(en, 3) - __shfl(st, 3));

    float s0x = 0.f, s0y = 0.f, s1x = 0.f, s1y = 0.f;
    float s2x = 0.f, s2y = 0.f, s3x = 0.f, s3y = 0.f;

    for (int b = start; b < end; b += 8) {
        int pidx = b + (lane & 7);
        int pl = perm[pidx < end ? pidx : end - 1];
        int nb = end - b;               // wave-uniform
        float2 r[8];
        int tt[8];
#pragma unroll
        for (int i = 0; i < 8; ++i) {
            if (i < nb) {
                int pk = __shfl(pl, i);
                int s = pk & 0xffff;
                tt[i] = pk >> 16;
                r[i] = ((const float2*)(H + (size_t)s * F))[lane];
            }
        }
#pragma unroll
        for (int i = 0; i < 8; ++i) {
            if (i < nb) {
                float fx = r[i].x, fy = r[i].y;
                int t = tt[i];
                if (t == 0)      { s0x += fx; s0y += fy; }
                else if (t == 1) { s1x += fx; s1y += fy; }
                else if (t == 2) { s2x += fx; s2y += fy; }
                else             { s3x += fx; s3y += fy; }
            }
        }
    }

    float i0 = 1.0f / fmaxf(c0, 1.0f);
    float i1 = 1.0f / fmaxf(c1, 1.0f);
    float i2 = 1.0f / fmaxf(c2, 1.0f);
    float i3 = 1.0f / fmaxf(c3, 1.0f);
    float2* ap = (float2*)(agg + (size_t)node * NT * F);
    ap[lane]           = make_float2(s0x * i0, s0y * i0);
    ap[64 + lane]      = make_float2(s1x * i1, s1y * i1);
    ap[128 + lane]     = make_float2(s2x * i2, s2y * i2);
    ap[192 + lane]     = make_float2(s3x * i3, s3y * i3);
}

// ---------------- MFMA GEMM, bf16x3 split-precision ----------------
// block 256 = 4 waves; tile 64 rows x 128 cols; wave w owns cols [w*32, w*32+32)
__global__ __launch_bounds__(256) void gemm_mfma(
    const float* __restrict__ X,             // [N,F] plane 0
    const float* __restrict__ agg,           // [N,NT,F] pre-scaled means (node-major)
    const unsigned short* __restrict__ Whsw, // [WELEM] frag-ordered hi (this layer)
    const unsigned short* __restrict__ Wlsw, // [WELEM] frag-ordered lo (this layer)
    const float* __restrict__ bias,          // [F]
    float* __restrict__ out,                 // [N,F]
    int doNormRelu)
{
    __shared__ unsigned short AhS[64][56];   // pitch 56: 16B-aligned frags, ~2-way banks
    __shared__ unsigned short AlS[64][56];
    __shared__ float redb[64][5];
    __shared__ float scl[64];

    const int tid = threadIdx.x;
    const int lane = tid & 63;
    const int w = tid >> 6;
    const int quad = lane >> 4;
    const int l15 = lane & 15;
    const int nodeBase = blockIdx.x * 64;

    f32x4 acc[4][2];
#pragma unroll
    for (int rt = 0; rt < 4; ++rt)
#pragma unroll
        for (int ci = 0; ci < 2; ++ci)
            acc[rt][ci] = (f32x4){0.f, 0.f, 0.f, 0.f};

    const bf16x8* Bh = (const bf16x8*)Whsw;
    const bf16x8* Bl = (const bf16x8*)Wlsw;

    for (int kt = 0; kt < NKT; ++kt) {
        const int p = kt >> 2;               // virtual-A plane
        const int kk0 = (kt & 3) * 32;
        __syncthreads();
#pragma unroll
        for (int i = 0; i < 2; ++i) {
            int idx = i * 256 + tid;
            int r = idx >> 3;
            int cc = (idx & 7) * 4;
            int n = nodeBase + r;
            int nc = n < N_NODES ? n : N_NODES - 1;
            const float* srcp = (p == 0)
                ? (X + (size_t)nc * F + kk0)
                : (agg + ((size_t)nc * NT + (p - 1)) * F + kk0);
            float4 v = *(const float4*)(srcp + cc);
            ushort4 hi, lo;
            hi.x = f2b(v.x); lo.x = f2b(v.x - b2f(hi.x));
            hi.y = f2b(v.y); lo.y = f2b(v.y - b2f(hi.y));
            hi.z = f2b(v.z); lo.z = f2b(v.z - b2f(hi.z));
            hi.w = f2b(v.w); lo.w = f2b(v.w - b2f(hi.w));
            *(ushort4*)&AhS[r][cc] = hi;
            *(ushort4*)&AlS[r][cc] = lo;
        }
        __syncthreads();

        bf16x8 bh[2], bl[2];
#pragma unroll
        for (int ci = 0; ci < 2; ++ci) {
            int fi = (kt * 8 + (w * 2 + ci)) * 64 + lane;
            bh[ci] = Bh[fi];
            bl[ci] = Bl[fi];
        }
        bf16x8 ah[4], al[4];
#pragma unroll
        for (int rt = 0; rt < 4; ++rt) {
            int row = rt * 16 + l15;
            ah[rt] = *(const bf16x8*)&AhS[row][quad * 8];
            al[rt] = *(const bf16x8*)&AlS[row][quad * 8];
        }
#pragma unroll
        for (int rt = 0; rt < 4; ++rt)
#pragma unroll
            for (int ci = 0; ci < 2; ++ci) {
                acc[rt][ci] = __builtin_amdgcn_mfma_f32_16x16x32_bf16(ah[rt], bh[ci], acc[rt][ci], 0, 0, 0);
                acc[rt][ci] = __builtin_amdgcn_mfma_f32_16x16x32_bf16(ah[rt], bl[ci], acc[rt][ci], 0, 0, 0);
                acc[rt][ci] = __builtin_amdgcn_mfma_f32_16x16x32_bf16(al[rt], bh[ci], acc[rt][ci], 0, 0, 0);
            }
    }

    // bias (before normalize, per reference)
    float b0 = bias[w * 32 + l15];
    float b1v = bias[w * 32 + 16 + l15];
#pragma unroll
    for (int rt = 0; rt < 4; ++rt)
#pragma unroll
        for (int r = 0; r < 4; ++r) {
            acc[rt][0][r] += b0;
            acc[rt][1][r] += b1v;
        }

    if (doNormRelu) {
#pragma unroll
        for (int rt = 0; rt < 4; ++rt)
#pragma unroll
            for (int r = 0; r < 4; ++r) {
                float v = acc[rt][0][r] * acc[rt][0][r] + acc[rt][1][r] * acc[rt][1][r];
                v += __shfl_xor(v, 1);
                v += __shfl_xor(v, 2);
                v += __shfl_xor(v, 4);
                v += __shfl_xor(v, 8);
                if (l15 == 0) redb[rt * 16 + quad * 4 + r][w] = v;
            }
        __syncthreads();
        if (tid < 64) {
            float s = redb[tid][0] + redb[tid][1] + redb[tid][2] + redb[tid][3];
            scl[tid] = 1.0f / fmaxf(sqrtf(s), 1e-12f);
        }
        __syncthreads();
#pragma unroll
        for (int rt = 0; rt < 4; ++rt)
#pragma unroll
            for (int r = 0; r < 4; ++r) {
                float sc = scl[rt * 16 + quad * 4 + r];
                acc[rt][0][r] = fmaxf(acc[rt][0][r] * sc, 0.0f);
                acc[rt][1][r] = fmaxf(acc[rt][1][r] * sc, 0.0f);
            }
    }

    // store: C/D layout col=lane&15, row=quad*4+reg
#pragma unroll
    for (int rt = 0; rt < 4; ++rt)
#pragma unroll
        for (int r = 0; r < 4; ++r) {
            int row = rt * 16 + quad * 4 + r;
            int n = nodeBase + row;
            if (n < N_NODES) {
                out[(size_t)n * F + w * 32 + l15] = acc[rt][0][r];
                out[(size_t)n * F + w * 32 + 16 + l15] = acc[rt][1][r];
            }
        }
}

extern "C" void kernel_launch(void* const* d_in, const int* in_sizes, int n_in,
                              void* d_out, int out_size, void* d_ws, size_t ws_size,
                              hipStream_t stream)
{
    const float* x   = (const float*)d_in[0];
    const float* Ws1 = (const float*)d_in[1];
    const float* Wn1 = (const float*)d_in[2];
    const float* b1  = (const float*)d_in[3];
    const float* Ws2 = (const float*)d_in[4];
    const float* Wn2 = (const float*)d_in[5];
    const float* b2  = (const float*)d_in[6];
    const int* edge_index = (const int*)d_in[7];
    const int* edge_type  = (const int*)d_in[8];

    const int* srcA = edge_index;
    const int* dstA = edge_index + N_EDGES;

    // workspace layout
    float* ws   = (float*)d_ws;
    float* agg  = ws;                                        // 25,600,000 f  [N,NT,F]
    float* h1   = agg + (size_t)NT * N_NODES * F;            //  6,400,000 f
    float* bavg = h1 + (size_t)N_NODES * F;                  //        256 f
    unsigned short* Whsw = (unsigned short*)(bavg + 2 * F);  // 2*WELEM u16
    unsigned short* Wlsw = Whsw + (size_t)2 * WELEM;         // 2*WELEM u16
    int* counts = (int*)(Wlsw + (size_t)2 * WELEM);          // N_SEG (becomes off in place)
    int* cursor = counts + N_SEG;                            // N_SEG
    int* bsum   = cursor + N_SEG;                            // 256
    int* perm   = bsum + 256;                                // N_EDGES
    int* off    = counts;                                    // alias after scan3

    // weights: split + swizzle
    {
        int totalThreads = 2 * NKT * 8 * 64 + 2 * F;         // 20736
        hipLaunchKernelGGL(build_w_mfma, dim3((totalThreads + 255) / 256), dim3(256), 0, stream,
                           Ws1, Wn1, b1, Ws2, Wn2, b2, Whsw, Wlsw, bavg);
    }

    // ---------- CSR build (once; shared by both layers) ----------
    hipMemsetAsync(counts, 0, (size_t)N_SEG * sizeof(int), stream);
    hipLaunchKernelGGL(hist_kernel, dim3((N_EDGES + 255) / 256), dim3(256), 0, stream,
                       dstA, edge_type, counts);
    hipLaunchKernelGGL(scan1, dim3(SCAN_BLK), dim3(256), 0, stream, counts, bsum);
    hipLaunchKernelGGL(scan2, dim3(1), dim3(256), 0, stream, bsum);
    hipLaunchKernelGGL(scan3, dim3((N_SEG + 255) / 256), dim3(256), 0, stream,
                       counts, bsum, cursor);
    hipLaunchKernelGGL(permute_kernel, dim3((N_EDGES + 255) / 256), dim3(256), 0, stream,
                       srcA, dstA, edge_type, cursor, perm);
    // off[seg] = start, cursor[seg] = end

    // ---------- layer 1 ----------
    hipLaunchKernelGGL(gather_agg, dim3((N_NODES + 3) / 4), dim3(256), 0, stream,
                       x, perm, off, cursor, agg);
    hipLaunchKernelGGL(gemm_mfma, dim3((N_NODES + 63) / 64), dim3(256), 0, stream,
                       x, agg, Whsw, Wlsw, bavg, h1, 1);

    // ---------- layer 2 ----------
    hipLaunchKernelGGL(gather_agg, dim3((N_NODES + 3) / 4), dim3(256), 0, stream,
                       h1, perm, off, cursor, agg);
    hipLaunchKernelGGL(gemm_mfma, dim3((N_NODES + 63) / 64), dim3(256), 0, stream,
                       h1, agg, Whsw + WELEM, Wlsw + WELEM, bavg + F, (float*)d_out, 0);
}

// Round 8
// 364.758 us; speedup vs baseline: 2.9509x; 1.0415x over previous
//
#include <hip/hip_runtime.h>
#include <math.h>

#define N_NODES 50000
#define N_EDGES 600000
#define F 128
#define NT 4
#define ZC 640                 // Z columns = 5 planes x 128
#define N_SEG (NT * N_NODES)   // 200000
#define SCAN_BLK 196           // ceil(N_SEG / 1024)
#define NKT 4                  // K chunks of 32 (K=128)
#define NCT 40                 // global 16-col tiles (640/16)
#define WELEM (NKT * NCT * 64 * 8)  // 81920 bf16 elements per layer

typedef __attribute__((ext_vector_type(8))) short bf16x8;
typedef __attribute__((ext_vector_type(4))) float f32x4;

__device__ __forceinline__ unsigned short f2b(float f) {
    unsigned u = __float_as_uint(f);
    return (unsigned short)((u + 0x7FFFu + ((u >> 16) & 1u)) >> 16);
}
__device__ __forceinline__ float b2f(unsigned short h) {
    return __uint_as_float(((unsigned)h) << 16);
}

// ---- build pre-swizzled, hi/lo-split combined weights B[128,640] + averaged bias ----
// frag fi = (kt*NCT + gct)*64 + lane; element j: B[kt*32 + (lane>>4)*8 + j][gct*16 + (lane&15)]
// B[k][c]: plane p=c>>7: p==0 -> 0.25*sum_t Wself_t[k][c&127]; else Wneigh_{p-1}[k][c&127]/4
__global__ __launch_bounds__(256) void build_w_mfma(
    const float* __restrict__ Ws1, const float* __restrict__ Wn1, const float* __restrict__ b1,
    const float* __restrict__ Ws2, const float* __restrict__ Wn2, const float* __restrict__ b2,
    unsigned short* __restrict__ Whsw, unsigned short* __restrict__ Wlsw,
    float* __restrict__ bavg)
{
    int idx = blockIdx.x * 256 + threadIdx.x;
    const int perLayer = NKT * NCT * 64;   // 10240 fragments
    if (idx < 2 * perLayer) {
        int l = idx >= perLayer;
        int rem = idx - l * perLayer;
        int lane = rem & 63;
        int gct = (rem >> 6) % NCT;
        int kt = (rem >> 6) / NCT;
        const float* Wsl = l ? Ws2 : Ws1;
        const float* Wnl = l ? Wn2 : Wn1;
        unsigned short* oh = Whsw + (size_t)l * WELEM + (size_t)rem * 8;
        unsigned short* ol = Wlsw + (size_t)l * WELEM + (size_t)rem * 8;
        int c = gct * 16 + (lane & 15);
        int p = c >> 7;
        int cc = c & (F - 1);
        int kbase = kt * 32 + (lane >> 4) * 8;
#pragma unroll
        for (int j = 0; j < 8; ++j) {
            int k = kbase + j;
            float v;
            if (p == 0) {
                v = 0.25f * (Wsl[(0 * F + k) * F + cc] + Wsl[(1 * F + k) * F + cc] +
                             Wsl[(2 * F + k) * F + cc] + Wsl[(3 * F + k) * F + cc]);
            } else {
                v = 0.25f * Wnl[((p - 1) * F + k) * F + cc];
            }
            unsigned short h = f2b(v);
            oh[j] = h;
            ol[j] = f2b(v - b2f(h));
        }
    } else {
        int k = idx - 2 * perLayer;
        if (k < 2 * F) {
            int l = k >> 7;
            int j = k & (F - 1);
            const float* bl = l ? b2 : b1;
            bavg[k] = 0.25f * (bl[j] + bl[F + j] + bl[2 * F + j] + bl[3 * F + j]);
        }
    }
}

// ---------------- CSR build: histogram over (dst,type) buckets: seg = dst*4 + t ----
__global__ __launch_bounds__(256) void hist_kernel(
    const int* __restrict__ dstA, const int* __restrict__ typA, int* __restrict__ counts)
{
    int e = blockIdx.x * 256 + threadIdx.x;
    if (e < N_EDGES) atomicAdd(&counts[dstA[e] * NT + typA[e]], 1);
}

__global__ __launch_bounds__(256) void scan1(int* __restrict__ counts, int* __restrict__ bsum)
{
    __shared__ int sh[256];
    int t = threadIdx.x;
    int base = blockIdx.x * 1024 + t * 4;
    int v[4];
    int tot = 0;
#pragma unroll
    for (int j = 0; j < 4; ++j) {
        int i = base + j;
        v[j] = (i < N_SEG) ? counts[i] : 0;
        tot += v[j];
    }
    sh[t] = tot;
    __syncthreads();
    for (int ofs = 1; ofs < 256; ofs <<= 1) {
        int add = (t >= ofs) ? sh[t - ofs] : 0;
        __syncthreads();
        sh[t] += add;
        __syncthreads();
    }
    int excl = (t > 0) ? sh[t - 1] : 0;
    if (t == 255) bsum[blockIdx.x] = sh[255];
#pragma unroll
    for (int j = 0; j < 4; ++j) {
        int i = base + j;
        if (i < N_SEG) counts[i] = excl;
        excl += v[j];
    }
}

__global__ __launch_bounds__(256) void scan2(int* __restrict__ bsum)
{
    __shared__ int sh[256];
    int t = threadIdx.x;
    sh[t] = (t < SCAN_BLK) ? bsum[t] : 0;
    __syncthreads();
    for (int ofs = 1; ofs < 256; ofs <<= 1) {
        int add = (t >= ofs) ? sh[t - ofs] : 0;
        __syncthreads();
        sh[t] += add;
        __syncthreads();
    }
    int excl = (t > 0) ? sh[t - 1] : 0;
    if (t < SCAN_BLK) bsum[t] = excl;
}

__global__ __launch_bounds__(256) void scan3(
    int* __restrict__ counts, const int* __restrict__ bsum, int* __restrict__ cursor)
{
    int i = blockIdx.x * 256 + threadIdx.x;
    if (i < N_SEG) {
        int v = counts[i] + bsum[i >> 10];
        counts[i] = v;
        cursor[i] = v;
    }
}

// permute: pack (src | t<<16) into bucket slot (src < 65536 ok: N_NODES=50000)
__global__ __launch_bounds__(256) void permute_kernel(
    const int* __restrict__ srcA, const int* __restrict__ dstA, const int* __restrict__ typA,
    int* __restrict__ cursor, int* __restrict__ perm)
{
    int e = blockIdx.x * 256 + threadIdx.x;
    if (e < N_EDGES) {
        int t = typA[e];
        int pos = atomicAdd(&cursor[dstA[e] * NT + t], 1);
        perm[pos] = srcA[e] | (t << 16);
    }
}

// ---------------- dense GEMM: Z[N,640] = X[N,128] @ B[128,640], bf16x3 split ----------
// grid (ceil(N/64), 5); block 256 = 4 waves; this block: rows 64, cols cp*128..+128
__global__ __launch_bounds__(256) void gemm_z(
    const float* __restrict__ Xf,             // fp32 input (layer 1) or unused
    const unsigned short* __restrict__ Xh,    // pre-split input (layer 2)
    const unsigned short* __restrict__ Xl,
    const unsigned short* __restrict__ Wh,    // frag-ordered hi (this layer)
    const unsigned short* __restrict__ Wl,    // frag-ordered lo
    unsigned short* __restrict__ Z,           // [N,640] bf16
    int fp32in)
{
    __shared__ unsigned short AhS[64][136];   // pitch 136: 16B-aligned, spread banks
    __shared__ unsigned short AlS[64][136];

    const int tid = threadIdx.x;
    const int lane = tid & 63;
    const int w = tid >> 6;
    const int quad = lane >> 4;
    const int l15 = lane & 15;
    const int nodeBase = blockIdx.x * 64;
    const int cp = blockIdx.y;                // col plane 0..4

    // stage full 64x128 A tile (hi/lo) once
    {
        int r = tid >> 2;
        int cb = (tid & 3) * 32;
        int n = nodeBase + r;
        int nc = n < N_NODES ? n : N_NODES - 1;
        if (fp32in) {
            const float* src = Xf + (size_t)nc * F;
#pragma unroll
            for (int i = 0; i < 8; ++i) {
                int cc = cb + i * 4;
                float4 v = *(const float4*)(src + cc);
                ushort4 hi, lo;
                hi.x = f2b(v.x); lo.x = f2b(v.x - b2f(hi.x));
                hi.y = f2b(v.y); lo.y = f2b(v.y - b2f(hi.y));
                hi.z = f2b(v.z); lo.z = f2b(v.z - b2f(hi.z));
                hi.w = f2b(v.w); lo.w = f2b(v.w - b2f(hi.w));
                *(ushort4*)&AhS[r][cc] = hi;
                *(ushort4*)&AlS[r][cc] = lo;
            }
        } else {
            const unsigned short* sh = Xh + (size_t)nc * F;
            const unsigned short* sl = Xl + (size_t)nc * F;
#pragma unroll
            for (int i = 0; i < 4; ++i) {
                int cc = cb + i * 8;
                *(uint4*)&AhS[r][cc] = *(const uint4*)(sh + cc);
                *(uint4*)&AlS[r][cc] = *(const uint4*)(sl + cc);
            }
        }
    }
    __syncthreads();

    f32x4 acc[4][2];
#pragma unroll
    for (int rt = 0; rt < 4; ++rt)
#pragma unroll
        for (int ci = 0; ci < 2; ++ci)
            acc[rt][ci] = (f32x4){0.f, 0.f, 0.f, 0.f};

    const bf16x8* Bh = (const bf16x8*)Wh;
    const bf16x8* Bl = (const bf16x8*)Wl;

#pragma unroll
    for (int kt = 0; kt < NKT; ++kt) {
        bf16x8 bh[2], bl[2];
#pragma unroll
        for (int ci = 0; ci < 2; ++ci) {
            int gct = cp * 8 + w * 2 + ci;
            int fi = (kt * NCT + gct) * 64 + lane;
            bh[ci] = Bh[fi];
            bl[ci] = Bl[fi];
        }
        bf16x8 ah[4], al[4];
#pragma unroll
        for (int rt = 0; rt < 4; ++rt) {
            int row = rt * 16 + l15;
            ah[rt] = *(const bf16x8*)&AhS[row][kt * 32 + quad * 8];
            al[rt] = *(const bf16x8*)&AlS[row][kt * 32 + quad * 8];
        }
#pragma unroll
        for (int rt = 0; rt < 4; ++rt)
#pragma unroll
            for (int ci = 0; ci < 2; ++ci) {
                acc[rt][ci] = __builtin_amdgcn_mfma_f32_16x16x32_bf16(ah[rt], bh[ci], acc[rt][ci], 0, 0, 0);
                acc[rt][ci] = __builtin_amdgcn_mfma_f32_16x16x32_bf16(ah[rt], bl[ci], acc[rt][ci], 0, 0, 0);
                acc[rt][ci] = __builtin_amdgcn_mfma_f32_16x16x32_bf16(al[rt], bh[ci], acc[rt][ci], 0, 0, 0);
            }
    }

    // store Z as bf16; C/D layout col=lane&15, row=quad*4+reg
#pragma unroll
    for (int rt = 0; rt < 4; ++rt)
#pragma unroll
        for (int r = 0; r < 4; ++r) {
            int row = rt * 16 + quad * 4 + r;
            int n = nodeBase + row;
            if (n < N_NODES) {
                size_t base = (size_t)n * ZC + cp * F + w * 32;
                Z[base + l15]      = f2b(acc[rt][0][r]);
                Z[base + 16 + l15] = f2b(acc[rt][1][r]);
            }
        }
}

// ---------------- gather+epilogue: one wave per node ----------------
// out[n] = Zself[n] + sum_t mean_{e in seg(n,t)} Zt[src_e] + bias; optional l2norm+relu
__global__ __launch_bounds__(256) void gather_out(
    const unsigned short* __restrict__ Z, const int* __restrict__ perm,
    const int* __restrict__ off, const int* __restrict__ segend,
    const float* __restrict__ bias,
    float* __restrict__ outF,                 // fp32 output (layer 2)
    unsigned short* __restrict__ outH,        // pre-split output (layer 1)
    unsigned short* __restrict__ outL,
    int doNormRelu)
{
    int node = blockIdx.x * 4 + (threadIdx.x >> 6);
    int lane = threadIdx.x & 63;
    if (node >= N_NODES) return;

    int st = 0, en = 0;
    if (lane < 4) {
        st = off[node * NT + lane];
        en = segend[node * NT + lane];
    }
    int start = __shfl(st, 0);
    int end   = __shfl(en, 3);
    float c0 = (float)(__shfl(en, 0) - __shfl(st, 0));
    float c1 = (float)(__shfl(en, 1) - __shfl(st, 1));
    float c2 = (float)(__shfl(en, 2) - __shfl(st, 2));
    float c3 = (float)(__shfl(en, 3) - __shfl(st, 3));

    // self term (plane 0), 2 bf16 per lane
    unsigned su = ((const unsigned*)(Z + (size_t)node * ZC))[lane];

    float s0x = 0.f, s0y = 0.f, s1x = 0.f, s1y = 0.f;
    float s2x = 0.f, s2y = 0.f, s3x = 0.f, s3y = 0.f;

    for (int b = start; b < end; b += 8) {
        int pidx = b + (lane & 7);
        int pl = perm[pidx < end ? pidx : end - 1];
        int nb = end - b;                     // wave-uniform
        unsigned u[8];
        int tt[8];
#pragma unroll
        for (int i = 0; i < 8; ++i) {
            if (i < nb) {
                int pk = __shfl(pl, i);
                int s = pk & 0xffff;
                tt[i] = pk >> 16;
                u[i] = ((const unsigned*)(Z + (size_t)s * ZC + (size_t)(tt[i] + 1) * F))[lane];
            }
        }
#pragma unroll
        for (int i = 0; i < 8; ++i) {
            if (i < nb) {
                float fx = b2f((unsigned short)(u[i] & 0xffffu));
                float fy = b2f((unsigned short)(u[i] >> 16));
                int t = tt[i];
                if (t == 0)      { s0x += fx; s0y += fy; }
                else if (t == 1) { s1x += fx; s1y += fy; }
                else if (t == 2) { s2x += fx; s2y += fy; }
                else             { s3x += fx; s3y += fy; }
            }
        }
    }

    float i0 = 1.0f / fmaxf(c0, 1.0f);
    float i1 = 1.0f / fmaxf(c1, 1.0f);
    float i2 = 1.0f / fmaxf(c2, 1.0f);
    float i3 = 1.0f / fmaxf(c3, 1.0f);

    float2 bv = ((const float2*)bias)[lane];
    float vx = b2f((unsigned short)(su & 0xffffu)) +
               s0x * i0 + s1x * i1 + s2x * i2 + s3x * i3 + bv.x;
    float vy = b2f((unsigned short)(su >> 16)) +
               s0y * i0 + s1y * i1 + s2y * i2 + s3y * i3 + bv.y;

    if (doNormRelu) {
        float loc = vx * vx + vy * vy;
#pragma unroll
        for (int ofs = 1; ofs < 64; ofs <<= 1) loc += __shfl_xor(loc, ofs);
        float sc = 1.0f / fmaxf(sqrtf(loc), 1e-12f);
        vx = fmaxf(vx * sc, 0.0f);
        vy = fmaxf(vy * sc, 0.0f);
        unsigned short hx = f2b(vx), hy = f2b(vy);
        unsigned short lx = f2b(vx - b2f(hx)), ly = f2b(vy - b2f(hy));
        ((unsigned*)(outH + (size_t)node * F))[lane] = (unsigned)hx | ((unsigned)hy << 16);
        ((unsigned*)(outL + (size_t)node * F))[lane] = (unsigned)lx | ((unsigned)ly << 16);
    } else {
        ((float2*)(outF + (size_t)node * F))[lane] = make_float2(vx, vy);
    }
}

extern "C" void kernel_launch(void* const* d_in, const int* in_sizes, int n_in,
                              void* d_out, int out_size, void* d_ws, size_t ws_size,
                              hipStream_t stream)
{
    const float* x   = (const float*)d_in[0];
    const float* Ws1 = (const float*)d_in[1];
    const float* Wn1 = (const float*)d_in[2];
    const float* b1  = (const float*)d_in[3];
    const float* Ws2 = (const float*)d_in[4];
    const float* Wn2 = (const float*)d_in[5];
    const float* b2  = (const float*)d_in[6];
    const int* edge_index = (const int*)d_in[7];
    const int* edge_type  = (const int*)d_in[8];

    const int* srcA = edge_index;
    const int* dstA = edge_index + N_EDGES;

    // workspace layout (all 16B-aligned)
    unsigned short* Z   = (unsigned short*)d_ws;             // N*640 u16 = 64.0 MB
    unsigned short* h1h = Z + (size_t)N_NODES * ZC;          // N*128 u16 = 12.8 MB
    unsigned short* h1l = h1h + (size_t)N_NODES * F;         // N*128 u16
    float* bavg = (float*)(h1l + (size_t)N_NODES * F);       // 256 f
    unsigned short* Whsw = (unsigned short*)(bavg + 2 * F);  // 2*WELEM u16
    unsigned short* Wlsw = Whsw + (size_t)2 * WELEM;         // 2*WELEM u16
    int* counts = (int*)(Wlsw + (size_t)2 * WELEM);          // N_SEG (becomes off)
    int* cursor = counts + N_SEG;                            // N_SEG
    int* bsum   = cursor + N_SEG;                            // 256
    int* perm   = bsum + 256;                                // N_EDGES
    int* off    = counts;                                    // alias after scan3

    // weights: combine + split + swizzle
    {
        int totalThreads = 2 * NKT * NCT * 64 + 2 * F;       // 20736
        hipLaunchKernelGGL(build_w_mfma, dim3((totalThreads + 255) / 256), dim3(256), 0, stream,
                           Ws1, Wn1, b1, Ws2, Wn2, b2, Whsw, Wlsw, bavg);
    }

    // ---------- CSR build (once; shared by both layers) ----------
    hipMemsetAsync(counts, 0, (size_t)N_SEG * sizeof(int), stream);
    hipLaunchKernelGGL(hist_kernel, dim3((N_EDGES + 255) / 256), dim3(256), 0, stream,
                       dstA, edge_type, counts);
    hipLaunchKernelGGL(scan1, dim3(SCAN_BLK), dim3(256), 0, stream, counts, bsum);
    hipLaunchKernelGGL(scan2, dim3(1), dim3(256), 0, stream, bsum);
    hipLaunchKernelGGL(scan3, dim3((N_SEG + 255) / 256), dim3(256), 0, stream,
                       counts, bsum, cursor);
    hipLaunchKernelGGL(permute_kernel, dim3((N_EDGES + 255) / 256), dim3(256), 0, stream,
                       srcA, dstA, edge_type, cursor, perm);
    // off[seg] = start, cursor[seg] = end

    const int gemmGridX = (N_NODES + 63) / 64;               // 782

    // ---------- layer 1 ----------
    hipLaunchKernelGGL(gemm_z, dim3(gemmGridX, 5), dim3(256), 0, stream,
                       x, (const unsigned short*)nullptr, (const unsigned short*)nullptr,
                       Whsw, Wlsw, Z, 1);
    hipLaunchKernelGGL(gather_out, dim3((N_NODES + 3) / 4), dim3(256), 0, stream,
                       Z, perm, off, cursor, bavg, (float*)nullptr, h1h, h1l, 1);

    // ---------- layer 2 ----------
    hipLaunchKernelGGL(gemm_z, dim3(gemmGridX, 5), dim3(256), 0, stream,
                       (const float*)nullptr, h1h, h1l,
                       Whsw + WELEM, Wlsw + WELEM, Z, 0);
    hipLaunchKernelGGL(gather_out, dim3((N_NODES + 3) / 4), dim3(256), 0, stream,
                       Z, perm, off, cursor, bavg + F, (float*)d_out,
                       (unsigned short*)nullptr, (unsigned short*)nullptr, 0);
}

// Round 9
// 341.503 us; speedup vs baseline: 3.1519x; 1.0681x over previous
//
#include <hip/hip_runtime.h>
#include <math.h>

#define N_NODES 50000
#define N_EDGES 600000
#define F 128
#define NT 4
#define ZC 640                 // Z columns = 5 planes x 128
#define N_SEG (NT * N_NODES)   // 200000
#define SCAN_BLK 196           // ceil(N_SEG / 1024)
#define NKT 4                  // K chunks of 32 (K=128)
#define NCT 40                 // global 16-col tiles (640/16)
#define WELEM (NKT * NCT * 64 * 8)  // 81920 bf16 elements per layer

typedef __attribute__((ext_vector_type(8))) short bf16x8;
typedef __attribute__((ext_vector_type(4))) float f32x4;

__device__ __forceinline__ unsigned short f2b(float f) {
    unsigned u = __float_as_uint(f);
    return (unsigned short)((u + 0x7FFFu + ((u >> 16) & 1u)) >> 16);
}
__device__ __forceinline__ float b2f(unsigned short h) {
    return __uint_as_float(((unsigned)h) << 16);
}

// ---- build pre-swizzled, hi/lo-split combined weights B[128,640] + averaged bias ----
__global__ __launch_bounds__(256) void build_w_mfma(
    const float* __restrict__ Ws1, const float* __restrict__ Wn1, const float* __restrict__ b1,
    const float* __restrict__ Ws2, const float* __restrict__ Wn2, const float* __restrict__ b2,
    unsigned short* __restrict__ Whsw, unsigned short* __restrict__ Wlsw,
    float* __restrict__ bavg)
{
    int idx = blockIdx.x * 256 + threadIdx.x;
    const int perLayer = NKT * NCT * 64;   // 10240 fragments
    if (idx < 2 * perLayer) {
        int l = idx >= perLayer;
        int rem = idx - l * perLayer;
        int lane = rem & 63;
        int gct = (rem >> 6) % NCT;
        int kt = (rem >> 6) / NCT;
        const float* Wsl = l ? Ws2 : Ws1;
        const float* Wnl = l ? Wn2 : Wn1;
        unsigned short* oh = Whsw + (size_t)l * WELEM + (size_t)rem * 8;
        unsigned short* ol = Wlsw + (size_t)l * WELEM + (size_t)rem * 8;
        int c = gct * 16 + (lane & 15);
        int p = c >> 7;
        int cc = c & (F - 1);
        int kbase = kt * 32 + (lane >> 4) * 8;
#pragma unroll
        for (int j = 0; j < 8; ++j) {
            int k = kbase + j;
            float v;
            if (p == 0) {
                v = 0.25f * (Wsl[(0 * F + k) * F + cc] + Wsl[(1 * F + k) * F + cc] +
                             Wsl[(2 * F + k) * F + cc] + Wsl[(3 * F + k) * F + cc]);
            } else {
                v = 0.25f * Wnl[((p - 1) * F + k) * F + cc];
            }
            unsigned short h = f2b(v);
            oh[j] = h;
            ol[j] = f2b(v - b2f(h));
        }
    } else {
        int k = idx - 2 * perLayer;
        if (k < 2 * F) {
            int l = k >> 7;
            int j = k & (F - 1);
            const float* bl = l ? b2 : b1;
            bavg[k] = 0.25f * (bl[j] + bl[F + j] + bl[2 * F + j] + bl[3 * F + j]);
        }
    }
}

// ---------------- CSR build: histogram over (dst,type) buckets: seg = dst*4 + t ----
__global__ __launch_bounds__(256) void hist_kernel(
    const int* __restrict__ dstA, const int* __restrict__ typA, int* __restrict__ counts)
{
    int e = blockIdx.x * 256 + threadIdx.x;
    if (e < N_EDGES) atomicAdd(&counts[dstA[e] * NT + typA[e]], 1);
}

__global__ __launch_bounds__(256) void scan1(int* __restrict__ counts, int* __restrict__ bsum)
{
    __shared__ int sh[256];
    int t = threadIdx.x;
    int base = blockIdx.x * 1024 + t * 4;
    int v[4];
    int tot = 0;
#pragma unroll
    for (int j = 0; j < 4; ++j) {
        int i = base + j;
        v[j] = (i < N_SEG) ? counts[i] : 0;
        tot += v[j];
    }
    sh[t] = tot;
    __syncthreads();
    for (int ofs = 1; ofs < 256; ofs <<= 1) {
        int add = (t >= ofs) ? sh[t - ofs] : 0;
        __syncthreads();
        sh[t] += add;
        __syncthreads();
    }
    int excl = (t > 0) ? sh[t - 1] : 0;
    if (t == 255) bsum[blockIdx.x] = sh[255];
#pragma unroll
    for (int j = 0; j < 4; ++j) {
        int i = base + j;
        if (i < N_SEG) counts[i] = excl;
        excl += v[j];
    }
}

__global__ __launch_bounds__(256) void scan2(int* __restrict__ bsum)
{
    __shared__ int sh[256];
    int t = threadIdx.x;
    sh[t] = (t < SCAN_BLK) ? bsum[t] : 0;
    __syncthreads();
    for (int ofs = 1; ofs < 256; ofs <<= 1) {
        int add = (t >= ofs) ? sh[t - ofs] : 0;
        __syncthreads();
        sh[t] += add;
        __syncthreads();
    }
    int excl = (t > 0) ? sh[t - 1] : 0;
    if (t < SCAN_BLK) bsum[t] = excl;
}

__global__ __launch_bounds__(256) void scan3(
    int* __restrict__ counts, const int* __restrict__ bsum, int* __restrict__ cursor)
{
    int i = blockIdx.x * 256 + threadIdx.x;
    if (i < N_SEG) {
        int v = counts[i] + bsum[i >> 10];
        counts[i] = v;
        cursor[i] = v;
    }
}

// inv_make: inv[seg] = 1/max(cnt,1) from adjacent offsets (off finalized by scan3)
__global__ __launch_bounds__(256) void inv_make(
    const int* __restrict__ off, float* __restrict__ inv)
{
    int i = blockIdx.x * 256 + threadIdx.x;
    if (i < N_SEG) {
        int nxt = (i + 1 < N_SEG) ? off[i + 1] : N_EDGES;
        inv[i] = 1.0f / fmaxf((float)(nxt - off[i]), 1.0f);
    }
}

// permute: pack (fp32 scale bits << 32) | element-offset into bucket slot
__global__ __launch_bounds__(256) void permute_kernel(
    const int* __restrict__ srcA, const int* __restrict__ dstA, const int* __restrict__ typA,
    const float* __restrict__ inv, int* __restrict__ cursor,
    unsigned long long* __restrict__ perm64)
{
    int e = blockIdx.x * 256 + threadIdx.x;
    if (e < N_EDGES) {
        int t = typA[e];
        int seg = dstA[e] * NT + t;
        int pos = atomicAdd(&cursor[seg], 1);
        unsigned offw = (unsigned)(srcA[e] * ZC + (t + 1) * F);
        perm64[pos] = ((unsigned long long)__float_as_uint(inv[seg]) << 32) | offw;
    }
}

// ---------------- dense GEMM: Z[N,640] = X[N,128] @ B[128,640], bf16x3 split ----------
// grid (ceil(N/64), 5); block 256 = 4 waves; this block: rows 64, cols cp*128..+128
__global__ __launch_bounds__(256) void gemm_z(
    const float* __restrict__ Xf,             // fp32 input (layer 1) or unused
    const unsigned short* __restrict__ Xh,    // pre-split input (layer 2)
    const unsigned short* __restrict__ Xl,
    const unsigned short* __restrict__ Wh,    // frag-ordered hi (this layer)
    const unsigned short* __restrict__ Wl,    // frag-ordered lo
    unsigned short* __restrict__ Z,           // [N,640] bf16
    int fp32in)
{
    __shared__ unsigned short AhS[64][136];   // pitch 136: 16B-aligned, spread banks
    __shared__ unsigned short AlS[64][136];

    const int tid = threadIdx.x;
    const int lane = tid & 63;
    const int w = tid >> 6;
    const int quad = lane >> 4;
    const int l15 = lane & 15;
    const int nodeBase = blockIdx.x * 64;
    const int cp = blockIdx.y;                // col plane 0..4

    // stage full 64x128 A tile (hi/lo) once
    {
        int r = tid >> 2;
        int cb = (tid & 3) * 32;
        int n = nodeBase + r;
        int nc = n < N_NODES ? n : N_NODES - 1;
        if (fp32in) {
            const float* src = Xf + (size_t)nc * F;
#pragma unroll
            for (int i = 0; i < 8; ++i) {
                int cc = cb + i * 4;
                float4 v = *(const float4*)(src + cc);
                ushort4 hi, lo;
                hi.x = f2b(v.x); lo.x = f2b(v.x - b2f(hi.x));
                hi.y = f2b(v.y); lo.y = f2b(v.y - b2f(hi.y));
                hi.z = f2b(v.z); lo.z = f2b(v.z - b2f(hi.z));
                hi.w = f2b(v.w); lo.w = f2b(v.w - b2f(hi.w));
                *(ushort4*)&AhS[r][cc] = hi;
                *(ushort4*)&AlS[r][cc] = lo;
            }
        } else {
            const unsigned short* sh = Xh + (size_t)nc * F;
            const unsigned short* sl = Xl + (size_t)nc * F;
#pragma unroll
            for (int i = 0; i < 4; ++i) {
                int cc = cb + i * 8;
                *(uint4*)&AhS[r][cc] = *(const uint4*)(sh + cc);
                *(uint4*)&AlS[r][cc] = *(const uint4*)(sl + cc);
            }
        }
    }
    __syncthreads();

    f32x4 acc[4][2];
#pragma unroll
    for (int rt = 0; rt < 4; ++rt)
#pragma unroll
        for (int ci = 0; ci < 2; ++ci)
            acc[rt][ci] = (f32x4){0.f, 0.f, 0.f, 0.f};

    const bf16x8* Bh = (const bf16x8*)Wh;
    const bf16x8* Bl = (const bf16x8*)Wl;

#pragma unroll
    for (int kt = 0; kt < NKT; ++kt) {
        bf16x8 bh[2], bl[2];
#pragma unroll
        for (int ci = 0; ci < 2; ++ci) {
            int gct = cp * 8 + w * 2 + ci;
            int fi = (kt * NCT + gct) * 64 + lane;
            bh[ci] = Bh[fi];
            bl[ci] = Bl[fi];
        }
        bf16x8 ah[4], al[4];
#pragma unroll
        for (int rt = 0; rt < 4; ++rt) {
            int row = rt * 16 + l15;
            ah[rt] = *(const bf16x8*)&AhS[row][kt * 32 + quad * 8];
            al[rt] = *(const bf16x8*)&AlS[row][kt * 32 + quad * 8];
        }
#pragma unroll
        for (int rt = 0; rt < 4; ++rt)
#pragma unroll
            for (int ci = 0; ci < 2; ++ci) {
                acc[rt][ci] = __builtin_amdgcn_mfma_f32_16x16x32_bf16(ah[rt], bh[ci], acc[rt][ci], 0, 0, 0);
                acc[rt][ci] = __builtin_amdgcn_mfma_f32_16x16x32_bf16(ah[rt], bl[ci], acc[rt][ci], 0, 0, 0);
                acc[rt][ci] = __builtin_amdgcn_mfma_f32_16x16x32_bf16(al[rt], bh[ci], acc[rt][ci], 0, 0, 0);
            }
    }

    // store Z as bf16; C/D layout col=lane&15, row=quad*4+reg
#pragma unroll
    for (int rt = 0; rt < 4; ++rt)
#pragma unroll
        for (int r = 0; r < 4; ++r) {
            int row = rt * 16 + quad * 4 + r;
            int n = nodeBase + row;
            if (n < N_NODES) {
                size_t base = (size_t)n * ZC + cp * F + w * 32;
                Z[base + l15]      = f2b(acc[rt][0][r]);
                Z[base + 16 + l15] = f2b(acc[rt][1][r]);
            }
        }
}

// ---------------- gather+epilogue: one wave per node, pre-scaled edges ----------------
// out[n] = Zself[n] + sum_e scale_e * Z[off_e] + bias; optional l2norm+relu
__global__ __launch_bounds__(256) void gather_out(
    const unsigned short* __restrict__ Z,
    const unsigned long long* __restrict__ perm64,
    const int* __restrict__ off, const int* __restrict__ segend,
    const float* __restrict__ bias,
    float* __restrict__ outF,                 // fp32 output (layer 2)
    unsigned short* __restrict__ outH,        // pre-split output (layer 1)
    unsigned short* __restrict__ outL,
    int doNormRelu)
{
    int node = blockIdx.x * 4 + (threadIdx.x >> 6);
    int lane = threadIdx.x & 63;
    if (node >= N_NODES) return;

    // node's full edge range (wave-uniform scalar loads)
    int start = off[node * NT];
    int end   = segend[node * NT + NT - 1];

    // self term (plane 0), 2 bf16 per lane
    unsigned su = ((const unsigned*)(Z + (size_t)node * ZC))[lane];

    float sx = 0.f, sy = 0.f;
    const uint2* P = (const uint2*)perm64;

    for (int b = start; b < end; b += 8) {
        int pidx = b + (lane & 7);
        uint2 pk = P[pidx < end ? pidx : end - 1];
        int nb = end - b;                     // wave-uniform
        unsigned uv[8];
        float scl[8];
#pragma unroll
        for (int i = 0; i < 8; ++i) {
            if (i < nb) {
                unsigned offw = __shfl(pk.x, i);
                scl[i] = __uint_as_float(__shfl(pk.y, i));
                uv[i] = ((const unsigned*)(Z + offw))[lane];
            }
        }
#pragma unroll
        for (int i = 0; i < 8; ++i) {
            if (i < nb) {
                sx = fmaf(__uint_as_float(uv[i] << 16), scl[i], sx);
                sy = fmaf(__uint_as_float(uv[i] & 0xffff0000u), scl[i], sy);
            }
        }
    }

    float2 bv = ((const float2*)bias)[lane];
    float vx = __uint_as_float(su << 16) + sx + bv.x;
    float vy = __uint_as_float(su & 0xffff0000u) + sy + bv.y;

    if (doNormRelu) {
        float loc = vx * vx + vy * vy;
#pragma unroll
        for (int ofs = 1; ofs < 64; ofs <<= 1) loc += __shfl_xor(loc, ofs);
        float sc = 1.0f / fmaxf(sqrtf(loc), 1e-12f);
        vx = fmaxf(vx * sc, 0.0f);
        vy = fmaxf(vy * sc, 0.0f);
        unsigned short hx = f2b(vx), hy = f2b(vy);
        unsigned short lx = f2b(vx - b2f(hx)), ly = f2b(vy - b2f(hy));
        ((unsigned*)(outH + (size_t)node * F))[lane] = (unsigned)hx | ((unsigned)hy << 16);
        ((unsigned*)(outL + (size_t)node * F))[lane] = (unsigned)lx | ((unsigned)ly << 16);
    } else {
        ((float2*)(outF + (size_t)node * F))[lane] = make_float2(vx, vy);
    }
}

extern "C" void kernel_launch(void* const* d_in, const int* in_sizes, int n_in,
                              void* d_out, int out_size, void* d_ws, size_t ws_size,
                              hipStream_t stream)
{
    const float* x   = (const float*)d_in[0];
    const float* Ws1 = (const float*)d_in[1];
    const float* Wn1 = (const float*)d_in[2];
    const float* b1  = (const float*)d_in[3];
    const float* Ws2 = (const float*)d_in[4];
    const float* Wn2 = (const float*)d_in[5];
    const float* b2  = (const float*)d_in[6];
    const int* edge_index = (const int*)d_in[7];
    const int* edge_type  = (const int*)d_in[8];

    const int* srcA = edge_index;
    const int* dstA = edge_index + N_EDGES;

    // workspace layout (perm64 8B-aligned: all preceding sizes are multiples of 8B)
    unsigned short* Z   = (unsigned short*)d_ws;             // N*640 u16 = 64.0 MB
    unsigned short* h1h = Z + (size_t)N_NODES * ZC;          // N*128 u16
    unsigned short* h1l = h1h + (size_t)N_NODES * F;         // N*128 u16
    float* bavg = (float*)(h1l + (size_t)N_NODES * F);       // 256 f
    unsigned short* Whsw = (unsigned short*)(bavg + 2 * F);  // 2*WELEM u16
    unsigned short* Wlsw = Whsw + (size_t)2 * WELEM;         // 2*WELEM u16
    int* counts = (int*)(Wlsw + (size_t)2 * WELEM);          // N_SEG (becomes off)
    int* cursor = counts + N_SEG;                            // N_SEG
    int* bsum   = cursor + N_SEG;                            // 256
    float* inv  = (float*)(bsum + 256);                      // N_SEG
    unsigned long long* perm64 = (unsigned long long*)(inv + N_SEG);  // N_EDGES u64
    int* off    = counts;                                    // alias after scan3

    // weights: combine + split + swizzle
    {
        int totalThreads = 2 * NKT * NCT * 64 + 2 * F;       // 20736
        hipLaunchKernelGGL(build_w_mfma, dim3((totalThreads + 255) / 256), dim3(256), 0, stream,
                           Ws1, Wn1, b1, Ws2, Wn2, b2, Whsw, Wlsw, bavg);
    }

    // ---------- CSR build (once; shared by both layers) ----------
    hipMemsetAsync(counts, 0, (size_t)N_SEG * sizeof(int), stream);
    hipLaunchKernelGGL(hist_kernel, dim3((N_EDGES + 255) / 256), dim3(256), 0, stream,
                       dstA, edge_type, counts);
    hipLaunchKernelGGL(scan1, dim3(SCAN_BLK), dim3(256), 0, stream, counts, bsum);
    hipLaunchKernelGGL(scan2, dim3(1), dim3(256), 0, stream, bsum);
    hipLaunchKernelGGL(scan3, dim3((N_SEG + 255) / 256), dim3(256), 0, stream,
                       counts, bsum, cursor);
    hipLaunchKernelGGL(inv_make, dim3((N_SEG + 255) / 256), dim3(256), 0, stream,
                       off, inv);
    hipLaunchKernelGGL(permute_kernel, dim3((N_EDGES + 255) / 256), dim3(256), 0, stream,
                       srcA, dstA, edge_type, inv, cursor, perm64);
    // off[seg] = start, cursor[seg] = end

    const int gemmGridX = (N_NODES + 63) / 64;               // 782

    // ---------- layer 1 ----------
    hipLaunchKernelGGL(gemm_z, dim3(gemmGridX, 5), dim3(256), 0, stream,
                       x, (const unsigned short*)nullptr, (const unsigned short*)nullptr,
                       Whsw, Wlsw, Z, 1);
    hipLaunchKernelGGL(gather_out, dim3((N_NODES + 3) / 4), dim3(256), 0, stream,
                       Z, perm64, off, cursor, bavg, (float*)nullptr, h1h, h1l, 1);

    // ---------- layer 2 ----------
    hipLaunchKernelGGL(gemm_z, dim3(gemmGridX, 5), dim3(256), 0, stream,
                       (const float*)nullptr, h1h, h1l,
                       Whsw + WELEM, Wlsw + WELEM, Z, 0);
    hipLaunchKernelGGL(gather_out, dim3((N_NODES + 3) / 4), dim3(256), 0, stream,
                       Z, perm64, off, cursor, bavg + F, (float*)d_out,
                       (unsigned short*)nullptr, (unsigned short*)nullptr, 0);
}

// Round 10
// 333.153 us; speedup vs baseline: 3.2309x; 1.0251x over previous
//
#include <hip/hip_runtime.h>
#include <math.h>

#define N_NODES 50000
#define N_EDGES 600000
#define F 128
#define NT 4
#define ZC 640                 // Z columns = 5 planes x 128
#define N_SEG (NT * N_NODES)   // 200000
#define SCAN_BLK 196           // ceil(N_SEG / 1024)
#define NKT 4                  // K chunks of 32 (K=128)
#define NCT 40                 // global 16-col tiles (640/16)
#define WELEM (NKT * NCT * 64 * 8)  // 81920 bf16 elements per layer

typedef __attribute__((ext_vector_type(8))) short bf16x8;
typedef __attribute__((ext_vector_type(4))) float f32x4;

__device__ __forceinline__ unsigned short f2b(float f) {
    unsigned u = __float_as_uint(f);
    return (unsigned short)((u + 0x7FFFu + ((u >> 16) & 1u)) >> 16);
}
__device__ __forceinline__ float b2f(unsigned short h) {
    return __uint_as_float(((unsigned)h) << 16);
}

// ---- build pre-swizzled, hi/lo-split combined weights B[128,640] + averaged bias ----
__global__ __launch_bounds__(256) void build_w_mfma(
    const float* __restrict__ Ws1, const float* __restrict__ Wn1, const float* __restrict__ b1,
    const float* __restrict__ Ws2, const float* __restrict__ Wn2, const float* __restrict__ b2,
    unsigned short* __restrict__ Whsw, unsigned short* __restrict__ Wlsw,
    float* __restrict__ bavg)
{
    int idx = blockIdx.x * 256 + threadIdx.x;
    const int perLayer = NKT * NCT * 64;   // 10240 fragments
    if (idx < 2 * perLayer) {
        int l = idx >= perLayer;
        int rem = idx - l * perLayer;
        int lane = rem & 63;
        int gct = (rem >> 6) % NCT;
        int kt = (rem >> 6) / NCT;
        const float* Wsl = l ? Ws2 : Ws1;
        const float* Wnl = l ? Wn2 : Wn1;
        unsigned short* oh = Whsw + (size_t)l * WELEM + (size_t)rem * 8;
        unsigned short* ol = Wlsw + (size_t)l * WELEM + (size_t)rem * 8;
        int c = gct * 16 + (lane & 15);
        int p = c >> 7;
        int cc = c & (F - 1);
        int kbase = kt * 32 + (lane >> 4) * 8;
#pragma unroll
        for (int j = 0; j < 8; ++j) {
            int k = kbase + j;
            float v;
            if (p == 0) {
                v = 0.25f * (Wsl[(0 * F + k) * F + cc] + Wsl[(1 * F + k) * F + cc] +
                             Wsl[(2 * F + k) * F + cc] + Wsl[(3 * F + k) * F + cc]);
            } else {
                v = 0.25f * Wnl[((p - 1) * F + k) * F + cc];
            }
            unsigned short h = f2b(v);
            oh[j] = h;
            ol[j] = f2b(v - b2f(h));
        }
    } else {
        int k = idx - 2 * perLayer;
        if (k < 2 * F) {
            int l = k >> 7;
            int j = k & (F - 1);
            const float* bl = l ? b2 : b1;
            bavg[k] = 0.25f * (bl[j] + bl[F + j] + bl[2 * F + j] + bl[3 * F + j]);
        }
    }
}

// ---------------- CSR build: histogram over (dst,type) buckets: seg = dst*4 + t ----
__global__ __launch_bounds__(256) void hist_kernel(
    const int* __restrict__ dstA, const int* __restrict__ typA, int* __restrict__ counts)
{
    int e = blockIdx.x * 256 + threadIdx.x;
    if (e < N_EDGES) atomicAdd(&counts[dstA[e] * NT + typA[e]], 1);
}

__global__ __launch_bounds__(256) void scan1(int* __restrict__ counts, int* __restrict__ bsum)
{
    __shared__ int sh[256];
    int t = threadIdx.x;
    int base = blockIdx.x * 1024 + t * 4;
    int v[4];
    int tot = 0;
#pragma unroll
    for (int j = 0; j < 4; ++j) {
        int i = base + j;
        v[j] = (i < N_SEG) ? counts[i] : 0;
        tot += v[j];
    }
    sh[t] = tot;
    __syncthreads();
    for (int ofs = 1; ofs < 256; ofs <<= 1) {
        int add = (t >= ofs) ? sh[t - ofs] : 0;
        __syncthreads();
        sh[t] += add;
        __syncthreads();
    }
    int excl = (t > 0) ? sh[t - 1] : 0;
    if (t == 255) bsum[blockIdx.x] = sh[255];
#pragma unroll
    for (int j = 0; j < 4; ++j) {
        int i = base + j;
        if (i < N_SEG) counts[i] = excl;
        excl += v[j];
    }
}

__global__ __launch_bounds__(256) void scan2(int* __restrict__ bsum)
{
    __shared__ int sh[256];
    int t = threadIdx.x;
    sh[t] = (t < SCAN_BLK) ? bsum[t] : 0;
    __syncthreads();
    for (int ofs = 1; ofs < 256; ofs <<= 1) {
        int add = (t >= ofs) ? sh[t - ofs] : 0;
        __syncthreads();
        sh[t] += add;
        __syncthreads();
    }
    int excl = (t > 0) ? sh[t - 1] : 0;
    if (t < SCAN_BLK) bsum[t] = excl;
}

// scan3: finalize offsets IN PLACE (counts -> off), copy to cursor, write end sentinel
__global__ __launch_bounds__(256) void scan3(
    int* __restrict__ counts, const int* __restrict__ bsum, int* __restrict__ cursor)
{
    int i = blockIdx.x * 256 + threadIdx.x;
    if (i < N_SEG) {
        int v = counts[i] + bsum[i >> 10];
        counts[i] = v;
        cursor[i] = v;
    }
    if (i == 0) counts[N_SEG] = N_EDGES;   // sentinel for cnt computation
}

// permute: pack (fp32 scale bits << 32) | element-offset into bucket slot
// scale computed from adjacent offsets (off has N_EDGES sentinel at [N_SEG])
__global__ __launch_bounds__(256) void permute_kernel(
    const int* __restrict__ srcA, const int* __restrict__ dstA, const int* __restrict__ typA,
    const int* __restrict__ off, int* __restrict__ cursor,
    unsigned long long* __restrict__ perm64)
{
    int e = blockIdx.x * 256 + threadIdx.x;
    if (e < N_EDGES) {
        int t = typA[e];
        int seg = dstA[e] * NT + t;
        int pos = atomicAdd(&cursor[seg], 1);
        float invv = 1.0f / fmaxf((float)(off[seg + 1] - off[seg]), 1.0f);
        unsigned offw = (unsigned)(srcA[e] * ZC + (t + 1) * F);
        perm64[pos] = ((unsigned long long)__float_as_uint(invv) << 32) | offw;
    }
}

// ---------------- dense GEMM: Z[N,640] = X[N,128] @ B[128,640], bf16x3 split ----------
// grid ceil(N/64); block 256 = 4 waves; A staged ONCE, 5 col-planes looped in-block
__global__ __launch_bounds__(256) void gemm_z(
    const float* __restrict__ Xf,             // fp32 input (layer 1) or unused
    const unsigned short* __restrict__ Xh,    // pre-split input (layer 2)
    const unsigned short* __restrict__ Xl,
    const unsigned short* __restrict__ Wh,    // frag-ordered hi (this layer)
    const unsigned short* __restrict__ Wl,    // frag-ordered lo
    unsigned short* __restrict__ Z,           // [N,640] bf16
    int fp32in)
{
    __shared__ unsigned short AhS[64][136];   // pitch 136: 16B-aligned, spread banks
    __shared__ unsigned short AlS[64][136];

    const int tid = threadIdx.x;
    const int lane = tid & 63;
    const int w = tid >> 6;
    const int quad = lane >> 4;
    const int l15 = lane & 15;
    const int nodeBase = blockIdx.x * 64;

    // stage full 64x128 A tile (hi/lo) once
    {
        int r = tid >> 2;
        int cb = (tid & 3) * 32;
        int n = nodeBase + r;
        int nc = n < N_NODES ? n : N_NODES - 1;
        if (fp32in) {
            const float* src = Xf + (size_t)nc * F;
#pragma unroll
            for (int i = 0; i < 8; ++i) {
                int cc = cb + i * 4;
                float4 v = *(const float4*)(src + cc);
                ushort4 hi, lo;
                hi.x = f2b(v.x); lo.x = f2b(v.x - b2f(hi.x));
                hi.y = f2b(v.y); lo.y = f2b(v.y - b2f(hi.y));
                hi.z = f2b(v.z); lo.z = f2b(v.z - b2f(hi.z));
                hi.w = f2b(v.w); lo.w = f2b(v.w - b2f(hi.w));
                *(ushort4*)&AhS[r][cc] = hi;
                *(ushort4*)&AlS[r][cc] = lo;
            }
        } else {
            const unsigned short* sh = Xh + (size_t)nc * F;
            const unsigned short* sl = Xl + (size_t)nc * F;
#pragma unroll
            for (int i = 0; i < 4; ++i) {
                int cc = cb + i * 8;
                *(uint4*)&AhS[r][cc] = *(const uint4*)(sh + cc);
                *(uint4*)&AlS[r][cc] = *(const uint4*)(sl + cc);
            }
        }
    }
    __syncthreads();

    const bf16x8* Bh = (const bf16x8*)Wh;
    const bf16x8* Bl = (const bf16x8*)Wl;

    for (int cp = 0; cp < 5; ++cp) {
        f32x4 acc[4][2];
#pragma unroll
        for (int rt = 0; rt < 4; ++rt)
#pragma unroll
            for (int ci = 0; ci < 2; ++ci)
                acc[rt][ci] = (f32x4){0.f, 0.f, 0.f, 0.f};

#pragma unroll
        for (int kt = 0; kt < NKT; ++kt) {
            bf16x8 bh[2], bl[2];
#pragma unroll
            for (int ci = 0; ci < 2; ++ci) {
                int gct = cp * 8 + w * 2 + ci;
                int fi = (kt * NCT + gct) * 64 + lane;
                bh[ci] = Bh[fi];
                bl[ci] = Bl[fi];
            }
            bf16x8 ah[4], al[4];
#pragma unroll
            for (int rt = 0; rt < 4; ++rt) {
                int row = rt * 16 + l15;
                ah[rt] = *(const bf16x8*)&AhS[row][kt * 32 + quad * 8];
                al[rt] = *(const bf16x8*)&AlS[row][kt * 32 + quad * 8];
            }
#pragma unroll
            for (int rt = 0; rt < 4; ++rt)
#pragma unroll
                for (int ci = 0; ci < 2; ++ci) {
                    acc[rt][ci] = __builtin_amdgcn_mfma_f32_16x16x32_bf16(ah[rt], bh[ci], acc[rt][ci], 0, 0, 0);
                    acc[rt][ci] = __builtin_amdgcn_mfma_f32_16x16x32_bf16(ah[rt], bl[ci], acc[rt][ci], 0, 0, 0);
                    acc[rt][ci] = __builtin_amdgcn_mfma_f32_16x16x32_bf16(al[rt], bh[ci], acc[rt][ci], 0, 0, 0);
                }
        }

        // store plane cp; C/D layout col=lane&15, row=quad*4+reg
#pragma unroll
        for (int rt = 0; rt < 4; ++rt)
#pragma unroll
            for (int r = 0; r < 4; ++r) {
                int row = rt * 16 + quad * 4 + r;
                int n = nodeBase + row;
                if (n < N_NODES) {
                    size_t base = (size_t)n * ZC + cp * F + w * 32;
                    Z[base + l15]      = f2b(acc[rt][0][r]);
                    Z[base + 16 + l15] = f2b(acc[rt][1][r]);
                }
            }
    }
}

// ---------------- gather+epilogue: one wave per node, pre-scaled edges, 16-deep MLP ----
__global__ __launch_bounds__(256) void gather_out(
    const unsigned short* __restrict__ Z,
    const unsigned long long* __restrict__ perm64,
    const int* __restrict__ off, const int* __restrict__ segend,
    const float* __restrict__ bias,
    float* __restrict__ outF,                 // fp32 output (layer 2)
    unsigned short* __restrict__ outH,        // pre-split output (layer 1)
    unsigned short* __restrict__ outL,
    int doNormRelu)
{
    int node = blockIdx.x * 4 + (threadIdx.x >> 6);
    int lane = threadIdx.x & 63;
    if (node >= N_NODES) return;

    int start = off[node * NT];
    int end   = segend[node * NT + NT - 1];

    // self term (plane 0), 2 bf16 per lane
    unsigned su = ((const unsigned*)(Z + (size_t)node * ZC))[lane];

    float sx = 0.f, sy = 0.f;
    const uint2* P = (const uint2*)perm64;

    for (int b = start; b < end; b += 16) {
        int pidx = b + (lane & 15);
        uint2 pk = P[pidx < end ? pidx : end - 1];
        int nb = end - b;                     // wave-uniform
        unsigned uv[16];
        float scl[16];
#pragma unroll
        for (int i = 0; i < 16; ++i) {
            if (i < nb) {
                unsigned offw = __shfl(pk.x, i);
                scl[i] = __uint_as_float(__shfl(pk.y, i));
                uv[i] = ((const unsigned*)(Z + offw))[lane];
            }
        }
#pragma unroll
        for (int i = 0; i < 16; ++i) {
            if (i < nb) {
                sx = fmaf(__uint_as_float(uv[i] << 16), scl[i], sx);
                sy = fmaf(__uint_as_float(uv[i] & 0xffff0000u), scl[i], sy);
            }
        }
    }

    float2 bv = ((const float2*)bias)[lane];
    float vx = __uint_as_float(su << 16) + sx + bv.x;
    float vy = __uint_as_float(su & 0xffff0000u) + sy + bv.y;

    if (doNormRelu) {
        float loc = vx * vx + vy * vy;
#pragma unroll
        for (int ofs = 1; ofs < 64; ofs <<= 1) loc += __shfl_xor(loc, ofs);
        float sc = 1.0f / fmaxf(sqrtf(loc), 1e-12f);
        vx = fmaxf(vx * sc, 0.0f);
        vy = fmaxf(vy * sc, 0.0f);
        unsigned short hx = f2b(vx), hy = f2b(vy);
        unsigned short lx = f2b(vx - b2f(hx)), ly = f2b(vy - b2f(hy));
        ((unsigned*)(outH + (size_t)node * F))[lane] = (unsigned)hx | ((unsigned)hy << 16);
        ((unsigned*)(outL + (size_t)node * F))[lane] = (unsigned)lx | ((unsigned)ly << 16);
    } else {
        ((float2*)(outF + (size_t)node * F))[lane] = make_float2(vx, vy);
    }
}

extern "C" void kernel_launch(void* const* d_in, const int* in_sizes, int n_in,
                              void* d_out, int out_size, void* d_ws, size_t ws_size,
                              hipStream_t stream)
{
    const float* x   = (const float*)d_in[0];
    const float* Ws1 = (const float*)d_in[1];
    const float* Wn1 = (const float*)d_in[2];
    const float* b1  = (const float*)d_in[3];
    const float* Ws2 = (const float*)d_in[4];
    const float* Wn2 = (const float*)d_in[5];
    const float* b2  = (const float*)d_in[6];
    const int* edge_index = (const int*)d_in[7];
    const int* edge_type  = (const int*)d_in[8];

    const int* srcA = edge_index;
    const int* dstA = edge_index + N_EDGES;

    // workspace layout (all chunks keep perm64 8B-aligned)
    unsigned short* Z   = (unsigned short*)d_ws;             // N*640 u16 = 64.0 MB
    unsigned short* h1h = Z + (size_t)N_NODES * ZC;          // N*128 u16
    unsigned short* h1l = h1h + (size_t)N_NODES * F;         // N*128 u16
    float* bavg = (float*)(h1l + (size_t)N_NODES * F);       // 256 f
    unsigned short* Whsw = (unsigned short*)(bavg + 2 * F);  // 2*WELEM u16
    unsigned short* Wlsw = Whsw + (size_t)2 * WELEM;         // 2*WELEM u16
    int* counts = (int*)(Wlsw + (size_t)2 * WELEM);          // N_SEG+2 (off + sentinel + pad)
    int* cursor = counts + (N_SEG + 2);                      // N_SEG
    int* bsum   = cursor + N_SEG;                            // 256 -> total ints even
    unsigned long long* perm64 = (unsigned long long*)(bsum + 256);  // N_EDGES u64
    int* off    = counts;                                    // alias after scan3

    // weights: combine + split + swizzle
    {
        int totalThreads = 2 * NKT * NCT * 64 + 2 * F;       // 20736
        hipLaunchKernelGGL(build_w_mfma, dim3((totalThreads + 255) / 256), dim3(256), 0, stream,
                           Ws1, Wn1, b1, Ws2, Wn2, b2, Whsw, Wlsw, bavg);
    }

    // ---------- CSR build (once; shared by both layers) ----------
    hipMemsetAsync(counts, 0, (size_t)N_SEG * sizeof(int), stream);
    hipLaunchKernelGGL(hist_kernel, dim3((N_EDGES + 255) / 256), dim3(256), 0, stream,
                       dstA, edge_type, counts);
    hipLaunchKernelGGL(scan1, dim3(SCAN_BLK), dim3(256), 0, stream, counts, bsum);
    hipLaunchKernelGGL(scan2, dim3(1), dim3(256), 0, stream, bsum);
    hipLaunchKernelGGL(scan3, dim3((N_SEG + 255) / 256), dim3(256), 0, stream,
                       counts, bsum, cursor);
    hipLaunchKernelGGL(permute_kernel, dim3((N_EDGES + 255) / 256), dim3(256), 0, stream,
                       srcA, dstA, edge_type, off, cursor, perm64);
    // off[seg] = start, cursor[seg] = end

    const int gemmGridX = (N_NODES + 63) / 64;               // 782

    // ---------- layer 1 ----------
    hipLaunchKernelGGL(gemm_z, dim3(gemmGridX), dim3(256), 0, stream,
                       x, (const unsigned short*)nullptr, (const unsigned short*)nullptr,
                       Whsw, Wlsw, Z, 1);
    hipLaunchKernelGGL(gather_out, dim3((N_NODES + 3) / 4), dim3(256), 0, stream,
                       Z, perm64, off, cursor, bavg, (float*)nullptr, h1h, h1l, 1);

    // ---------- layer 2 ----------
    hipLaunchKernelGGL(gemm_z, dim3(gemmGridX), dim3(256), 0, stream,
                       (const float*)nullptr, h1h, h1l,
                       Whsw + WELEM, Wlsw + WELEM, Z, 0);
    hipLaunchKernelGGL(gather_out, dim3((N_NODES + 3) / 4), dim3(256), 0, stream,
                       Z, perm64, off, cursor, bavg + F, (float*)d_out,
                       (unsigned short*)nullptr, (unsigned short*)nullptr, 0);
}